// Round 2
// baseline (4635.597 us; speedup 1.0000x reference)
//
#include <hip/hip_runtime.h>
#include <math.h>

#define TS 64
#define KT 16

// ---- monotonic float<->uint encoding for atomicMax-based segment_max ----
__device__ __forceinline__ unsigned fenc(float f) {
    unsigned u = __float_as_uint(f);
    return (u & 0x80000000u) ? ~u : (u | 0x80000000u);
}
__device__ __forceinline__ float fdec(unsigned u) {
    return (u & 0x80000000u) ? __uint_as_float(u & 0x7FFFFFFFu) : __uint_as_float(~u);
}

// ---------------- GEMM: A[M,256] @ B[256,256], 64x64 tile, 256 thr ----------------
// MODE 0: out[M,256] = A@B + bias
// MODE 1: atomicAdd(scoreSlot, sum_rows q . tanh(relu(A)@B + bias))
// MODE 2: A' := attn[0]*relu(A) + attn[1]*relu(A2) (on the fly);
//         atomicAdd(out[row], sum_j relu((A'@B)[row,j]+bias[j]) * vq[j])   (vq = W2)
template<int MODE>
__launch_bounds__(256)
__global__ void gemm64(const float* __restrict__ A, const float* __restrict__ A2,
                       const float* __restrict__ B, const float* __restrict__ bias,
                       const float* __restrict__ vq, const float* __restrict__ attn2,
                       float* __restrict__ out, float* __restrict__ scoreSlot, int M)
{
    __shared__ float As[KT][TS + 4];
    __shared__ float Bs[KT][TS + 4];
    __shared__ float red[64 * 17];
    const int t   = threadIdx.x;
    const int tx  = t & 15, ty = t >> 4;
    const int row0 = blockIdx.x * TS;
    const int col0 = blockIdx.y * TS;

    float blend0 = 0.f, blend1 = 0.f;
    if (MODE == 2) { blend0 = attn2[0]; blend1 = attn2[1]; }

    float acc[4][4] = {};
    const int ar = t >> 2, ak = (t & 3) << 2;     // A tile load: 64 rows x 16 k
    const int bkk = t >> 4, bc = (t & 15) << 2;   // B tile load: 16 k x 64 cols
    const int arow = row0 + ar;

    for (int k0 = 0; k0 < 256; k0 += KT) {
        float4 av;
        if (arow < M) {
            av = *(const float4*)&A[(size_t)arow * 256 + k0 + ak];
            if (MODE >= 1) {  // GAT outputs pass through relu before use
                av.x = fmaxf(av.x, 0.f); av.y = fmaxf(av.y, 0.f);
                av.z = fmaxf(av.z, 0.f); av.w = fmaxf(av.w, 0.f);
            }
            if (MODE == 2) {
                float4 av2 = *(const float4*)&A2[(size_t)arow * 256 + k0 + ak];
                av.x = blend0 * av.x + blend1 * fmaxf(av2.x, 0.f);
                av.y = blend0 * av.y + blend1 * fmaxf(av2.y, 0.f);
                av.z = blend0 * av.z + blend1 * fmaxf(av2.z, 0.f);
                av.w = blend0 * av.w + blend1 * fmaxf(av2.w, 0.f);
            }
        } else {
            av = make_float4(0.f, 0.f, 0.f, 0.f);
        }
        As[ak + 0][ar] = av.x; As[ak + 1][ar] = av.y;
        As[ak + 2][ar] = av.z; As[ak + 3][ar] = av.w;
        *(float4*)&Bs[bkk][bc] = *(const float4*)&B[(size_t)(k0 + bkk) * 256 + col0 + bc];
        __syncthreads();
#pragma unroll
        for (int kk = 0; kk < KT; ++kk) {
            float4 a4 = *(const float4*)&As[kk][ty << 2];
            float4 b4 = *(const float4*)&Bs[kk][tx << 2];
            acc[0][0] += a4.x * b4.x; acc[0][1] += a4.x * b4.y; acc[0][2] += a4.x * b4.z; acc[0][3] += a4.x * b4.w;
            acc[1][0] += a4.y * b4.x; acc[1][1] += a4.y * b4.y; acc[1][2] += a4.y * b4.z; acc[1][3] += a4.y * b4.w;
            acc[2][0] += a4.z * b4.x; acc[2][1] += a4.z * b4.y; acc[2][2] += a4.z * b4.z; acc[2][3] += a4.z * b4.w;
            acc[3][0] += a4.w * b4.x; acc[3][1] += a4.w * b4.y; acc[3][2] += a4.w * b4.z; acc[3][3] += a4.w * b4.w;
        }
        __syncthreads();
    }

    const int cbase = col0 + (tx << 2);
    if (MODE == 0) {
        float4 b4 = *(const float4*)&bias[cbase];
#pragma unroll
        for (int i = 0; i < 4; ++i) {
            int r = row0 + (ty << 2) + i;
            if (r < M) {
                float4 v;
                v.x = acc[i][0] + b4.x; v.y = acc[i][1] + b4.y;
                v.z = acc[i][2] + b4.z; v.w = acc[i][3] + b4.w;
                *(float4*)&out[(size_t)r * 256 + cbase] = v;
            }
        }
    } else if (MODE == 1) {
        float4 b4 = *(const float4*)&bias[cbase];
        float4 q4 = *(const float4*)&vq[cbase];
        float p = 0.f;
#pragma unroll
        for (int i = 0; i < 4; ++i) {
            int r = row0 + (ty << 2) + i;
            if (r < M) {
                p += q4.x * tanhf(acc[i][0] + b4.x);
                p += q4.y * tanhf(acc[i][1] + b4.y);
                p += q4.z * tanhf(acc[i][2] + b4.z);
                p += q4.w * tanhf(acc[i][3] + b4.w);
            }
        }
#pragma unroll
        for (int off = 32; off > 0; off >>= 1) p += __shfl_xor(p, off);
        if ((t & 63) == 0) red[t >> 6] = p;
        __syncthreads();
        if (t == 0) atomicAdd(scoreSlot, red[0] + red[1] + red[2] + red[3]);
    } else { // MODE 2
        float4 b4 = *(const float4*)&bias[cbase];
        float4 w4 = *(const float4*)&vq[cbase];
#pragma unroll
        for (int i = 0; i < 4; ++i) {
            float s = fmaxf(acc[i][0] + b4.x, 0.f) * w4.x
                    + fmaxf(acc[i][1] + b4.y, 0.f) * w4.y
                    + fmaxf(acc[i][2] + b4.z, 0.f) * w4.z
                    + fmaxf(acc[i][3] + b4.w, 0.f) * w4.w;
            red[((ty << 2) + i) * 17 + tx] = s;
        }
        __syncthreads();
        if (t < 64) {
            float s = 0.f;
#pragma unroll
            for (int j = 0; j < 16; ++j) s += red[t * 17 + j];
            int r = row0 + t;
            if (r < M) atomicAdd(&out[r], s);
        }
    }
}

// ---------------- per-node attention logits: o_v[n,h] = dot(x[n,h,:], a_v[h,:]) ----------------
__launch_bounds__(256)
__global__ void node_al(const float* __restrict__ x, int N,
                        const float* __restrict__ a0, const float* __restrict__ a1,
                        const float* __restrict__ a2,
                        float* __restrict__ o0, float* __restrict__ o1, float* __restrict__ o2,
                        int nv)
{
    int wid  = (int)((blockIdx.x * 256 + threadIdx.x) >> 6);
    int lane = threadIdx.x & 63;
    if (wid >= N) return;
    float xv[4];
#pragma unroll
    for (int h = 0; h < 4; ++h) xv[h] = x[(size_t)wid * 256 + h * 64 + lane];
    for (int v = 0; v < nv; ++v) {
        const float* a = (v == 0) ? a0 : (v == 1 ? a1 : a2);
        float* o       = (v == 0) ? o0 : (v == 1 ? o1 : o2);
        float p0 = xv[0] * a[lane];
        float p1 = xv[1] * a[64 + lane];
        float p2 = xv[2] * a[128 + lane];
        float p3 = xv[3] * a[192 + lane];
#pragma unroll
        for (int off = 32; off > 0; off >>= 1) {
            p0 += __shfl_xor(p0, off);
            p1 += __shfl_xor(p1, off);
            p2 += __shfl_xor(p2, off);
            p3 += __shfl_xor(p3, off);
        }
        if (lane == 0) {
            o[(size_t)wid * 4 + 0] = p0;
            o[(size_t)wid * 4 + 1] = p1;
            o[(size_t)wid * 4 + 2] = p2;
            o[(size_t)wid * 4 + 3] = p3;
        }
    }
}

// ---------------- per-edge: leaky_relu logits + segment max ----------------
__launch_bounds__(256)
__global__ void edge_al_max(const float* __restrict__ als, const float* __restrict__ ald,
                            const int* __restrict__ src, const int* __restrict__ dst, int E,
                            float* __restrict__ ale, unsigned* __restrict__ amax)
{
    int e = blockIdx.x * 256 + threadIdx.x;
    if (e >= E) return;
    int s = src[e], d = dst[e];
    float4 a = *(const float4*)&als[(size_t)s * 4];
    float4 b = *(const float4*)&ald[(size_t)d * 4];
    float4 al;
    al.x = a.x + b.x; al.x = (al.x >= 0.f) ? al.x : 0.2f * al.x;
    al.y = a.y + b.y; al.y = (al.y >= 0.f) ? al.y : 0.2f * al.y;
    al.z = a.z + b.z; al.z = (al.z >= 0.f) ? al.z : 0.2f * al.z;
    al.w = a.w + b.w; al.w = (al.w >= 0.f) ? al.w : 0.2f * al.w;
    *(float4*)&ale[(size_t)e * 4] = al;
    atomicMax(&amax[(size_t)d * 4 + 0], fenc(al.x));
    atomicMax(&amax[(size_t)d * 4 + 1], fenc(al.y));
    atomicMax(&amax[(size_t)d * 4 + 2], fenc(al.z));
    atomicMax(&amax[(size_t)d * 4 + 3], fenc(al.w));
}

// ---------------- per-edge: e = exp(al - amax[dst]); denom[dst] += e ----------------
__launch_bounds__(256)
__global__ void edge_exp_denom(float* __restrict__ ale, const unsigned* __restrict__ amax,
                               const int* __restrict__ dst, int E, float* __restrict__ denom)
{
    int e = blockIdx.x * 256 + threadIdx.x;
    if (e >= E) return;
    int d = dst[e];
    float4 al = *(const float4*)&ale[(size_t)e * 4];
    uint4 am = *(const uint4*)&amax[(size_t)d * 4];
    float4 ex;
    ex.x = expf(al.x - fdec(am.x));
    ex.y = expf(al.y - fdec(am.y));
    ex.z = expf(al.z - fdec(am.z));
    ex.w = expf(al.w - fdec(am.w));
    *(float4*)&ale[(size_t)e * 4] = ex;
    atomicAdd(&denom[(size_t)d * 4 + 0], ex.x);
    atomicAdd(&denom[(size_t)d * 4 + 1], ex.y);
    atomicAdd(&denom[(size_t)d * 4 + 2], ex.z);
    atomicAdd(&denom[(size_t)d * 4 + 3], ex.w);
}

// ---------------- per-edge scatter: out[dst] += x_src[src] * alpha (1 wave/edge) ----------------
__launch_bounds__(256)
__global__ void edge_scatter(const float* __restrict__ xsrc, const float* __restrict__ ale,
                             const float* __restrict__ denom,
                             const int* __restrict__ src, const int* __restrict__ dst, int E,
                             float* __restrict__ outb)
{
    int w    = (int)((blockIdx.x * 256 + threadIdx.x) >> 6);
    int lane = threadIdx.x & 63;
    if (w >= E) return;
    int s = src[w], d = dst[w];
    int h = lane >> 4;
    float alpha = ale[(size_t)w * 4 + h] / (denom[(size_t)d * 4 + h] + 1e-16f);
    float4 x = *(const float4*)&xsrc[(size_t)s * 256 + (lane << 2)];
    float* o = &outb[(size_t)d * 256 + (lane << 2)];
    atomicAdd(o + 0, x.x * alpha);
    atomicAdd(o + 1, x.y * alpha);
    atomicAdd(o + 2, x.z * alpha);
    atomicAdd(o + 3, x.w * alpha);
}

__global__ void attn_k(const float* __restrict__ score, float* __restrict__ attn, float invN)
{
    if (threadIdx.x == 0 && blockIdx.x == 0) {
        float s0 = score[0] * invN, s1 = score[1] * invN;
        float m  = fmaxf(s0, s1);
        float e0 = expf(s0 - m), e1 = expf(s1 - m);
        float dsum = e0 + e1;
        attn[0] = e0 / dsum;
        attn[1] = e1 / dsum;
    }
}

__global__ void fill_out(float* __restrict__ o, const float* __restrict__ b2, int n)
{
    int i = blockIdx.x * 256 + threadIdx.x;
    if (i < n) o[i] = b2[0];
}

extern "C" void kernel_launch(void* const* d_in, const int* in_sizes, int n_in,
                              void* d_out, int out_size, void* d_ws, size_t ws_size,
                              hipStream_t stream)
{
    const float* x_job    = (const float*)d_in[0];
    const float* x_skill  = (const float*)d_in[1];
    const float* W_job    = (const float*)d_in[2];
    const float* b_job    = (const float*)d_in[3];
    const float* W_skill  = (const float*)d_in[4];
    const float* b_skill  = (const float*)d_in[5];
    const float* a_src_sj = (const float*)d_in[6];
    const float* a_dst_sj = (const float*)d_in[7];
    const float* a_src_jj = (const float*)d_in[8];
    const float* a_dst_jj = (const float*)d_in[9];
    // d_in[10], d_in[11]: a_src_js / a_dst_js — js edge type's output is unused by the head; skipped.
    const float* q_vec = (const float*)d_in[12];
    const float* Wk    = (const float*)d_in[13];
    const float* bk    = (const float*)d_in[14];
    const float* W1    = (const float*)d_in[15];
    const float* b1    = (const float*)d_in[16];
    const float* W2    = (const float*)d_in[17];
    const float* b2    = (const float*)d_in[18];
    const int* ei_sj_src = (const int*)d_in[19];
    const int* ei_sj_dst = (const int*)d_in[20];
    const int* ei_jj_src = (const int*)d_in[21];
    const int* ei_jj_dst = (const int*)d_in[22];

    const int NJ   = in_sizes[0] / 256;
    const int NS   = in_sizes[1] / 256;
    const int E_sj = in_sizes[19];
    const int E_jj = in_sizes[21];

    float* ws  = (float*)d_ws;
    size_t off = 0;
    auto alloc = [&](size_t n) { float* p = ws + off; off += (n + 63) & ~(size_t)63; return p; };
    float* h_job   = alloc((size_t)NJ * 256);
    float* h_skill = alloc((size_t)NS * 256);
    float* out_sj  = alloc((size_t)NJ * 256);
    float* out_jj  = alloc((size_t)NJ * 256);
    float* ald_sj  = alloc((size_t)NJ * 4);
    float* als_jj  = alloc((size_t)NJ * 4);
    float* ald_jj  = alloc((size_t)NJ * 4);
    float* als_sj  = alloc((size_t)NS * 4);
    unsigned* amax_sj = (unsigned*)alloc((size_t)NJ * 4);
    unsigned* amax_jj = (unsigned*)alloc((size_t)NJ * 4);
    float* den_sj = alloc((size_t)NJ * 4);
    float* den_jj = alloc((size_t)NJ * 4);
    float* ale_sj = alloc((size_t)E_sj * 4);
    float* ale_jj = alloc((size_t)E_jj * 4);
    float* score  = alloc(64);       // [0..1] = raw score sums, [2..3] = attn
    float* attn   = score + 2;
    (void)ws_size; (void)n_in;

    // zero accumulators (fresh every call — timed replays don't re-poison)
    hipMemsetAsync(out_sj,  0, (size_t)NJ * 256 * 4, stream);
    hipMemsetAsync(out_jj,  0, (size_t)NJ * 256 * 4, stream);
    hipMemsetAsync(amax_sj, 0, (size_t)NJ * 4 * 4, stream);
    hipMemsetAsync(amax_jj, 0, (size_t)NJ * 4 * 4, stream);
    hipMemsetAsync(den_sj,  0, (size_t)NJ * 4 * 4, stream);
    hipMemsetAsync(den_jj,  0, (size_t)NJ * 4 * 4, stream);
    hipMemsetAsync(score,   0, 2 * 4, stream);

    dim3 blk(256);
    int gmJ = (NJ + TS - 1) / TS, gmS = (NS + TS - 1) / TS;

    // input projections
    gemm64<0><<<dim3(gmJ, 4), blk, 0, stream>>>(x_job, nullptr, W_job, b_job,
                                                nullptr, nullptr, h_job, nullptr, NJ);
    gemm64<0><<<dim3(gmS, 4), blk, 0, stream>>>(x_skill, nullptr, W_skill, b_skill,
                                                nullptr, nullptr, h_skill, nullptr, NS);

    // node-level attention logits
    node_al<<<dim3((NJ * 64 + 255) / 256), blk, 0, stream>>>(
        h_job, NJ, a_dst_sj, a_src_jj, a_dst_jj, ald_sj, als_jj, ald_jj, 3);
    node_al<<<dim3((NS * 64 + 255) / 256), blk, 0, stream>>>(
        h_skill, NS, a_src_sj, nullptr, nullptr, als_sj, nullptr, nullptr, 1);

    // GAT sj: skill -> job
    edge_al_max<<<dim3((E_sj + 255) / 256), blk, 0, stream>>>(
        als_sj, ald_sj, ei_sj_src, ei_sj_dst, E_sj, ale_sj, amax_sj);
    // GAT jj: job -> job
    edge_al_max<<<dim3((E_jj + 255) / 256), blk, 0, stream>>>(
        als_jj, ald_jj, ei_jj_src, ei_jj_dst, E_jj, ale_jj, amax_jj);

    edge_exp_denom<<<dim3((E_sj + 255) / 256), blk, 0, stream>>>(
        ale_sj, amax_sj, ei_sj_dst, E_sj, den_sj);
    edge_exp_denom<<<dim3((E_jj + 255) / 256), blk, 0, stream>>>(
        ale_jj, amax_jj, ei_jj_dst, E_jj, den_jj);

    edge_scatter<<<dim3((E_sj + 3) / 4), blk, 0, stream>>>(
        h_skill, ale_sj, den_sj, ei_sj_src, ei_sj_dst, E_sj, out_sj);
    edge_scatter<<<dim3((E_jj + 3) / 4), blk, 0, stream>>>(
        h_job, ale_jj, den_jj, ei_jj_src, ei_jj_dst, E_jj, out_jj);

    // semantic attention scores (fused GEMM + tanh + q-dot + sum, relu on A)
    gemm64<1><<<dim3(gmJ, 4), blk, 0, stream>>>(out_sj, nullptr, Wk, bk,
                                                q_vec, nullptr, nullptr, &score[0], NJ);
    gemm64<1><<<dim3(gmJ, 4), blk, 0, stream>>>(out_jj, nullptr, Wk, bk,
                                                q_vec, nullptr, nullptr, &score[1], NJ);

    attn_k<<<1, 64, 0, stream>>>(score, attn, 1.0f / (float)NJ);

    // head: out = relu((attn0*relu(out_sj) + attn1*relu(out_jj)) @ W1 + b1) @ W2 + b2
    fill_out<<<dim3((out_size + 255) / 256), blk, 0, stream>>>((float*)d_out, b2, out_size);
    gemm64<2><<<dim3(gmJ, 4), blk, 0, stream>>>(out_sj, out_jj, W1, b1,
                                                W2, attn, (float*)d_out, nullptr, NJ);
}

// Round 3
// 1641.581 us; speedup vs baseline: 2.8239x; 2.8239x over previous
//
#include <hip/hip_runtime.h>
#include <math.h>

#define TS 64
#define KT 16
#define SCAN_B 256

// ---- monotonic float<->uint encoding for atomicMax-based segment_max ----
__device__ __forceinline__ unsigned fenc(float f) {
    unsigned u = __float_as_uint(f);
    return (u & 0x80000000u) ? ~u : (u | 0x80000000u);
}
__device__ __forceinline__ float fdec(unsigned u) {
    return (u & 0x80000000u) ? __uint_as_float(u & 0x7FFFFFFFu) : __uint_as_float(~u);
}

// ---------------- GEMM: A[M,256] @ B[256,256], 64x64 tile, 256 thr ----------------
// MODE 0: out[M,256] = A@B + bias
// MODE 1: atomicAdd(scoreSlot, sum_rows q . tanh(relu(A)@B + bias))
// MODE 2: A' := attn[0]*relu(A) + attn[1]*relu(A2) (on the fly);
//         atomicAdd(out[row], sum_j relu((A'@B)[row,j]+bias[j]) * vq[j])   (vq = W2)
template<int MODE>
__launch_bounds__(256)
__global__ void gemm64(const float* __restrict__ A, const float* __restrict__ A2,
                       const float* __restrict__ B, const float* __restrict__ bias,
                       const float* __restrict__ vq, const float* __restrict__ attn2,
                       float* __restrict__ out, float* __restrict__ scoreSlot, int M)
{
    __shared__ float As[KT][TS + 4];
    __shared__ float Bs[KT][TS + 4];
    __shared__ float red[64 * 17];
    const int t   = threadIdx.x;
    const int tx  = t & 15, ty = t >> 4;
    const int row0 = blockIdx.x * TS;
    const int col0 = blockIdx.y * TS;

    float blend0 = 0.f, blend1 = 0.f;
    if (MODE == 2) { blend0 = attn2[0]; blend1 = attn2[1]; }

    float acc[4][4] = {};
    const int ar = t >> 2, ak = (t & 3) << 2;     // A tile load: 64 rows x 16 k
    const int bkk = t >> 4, bc = (t & 15) << 2;   // B tile load: 16 k x 64 cols
    const int arow = row0 + ar;

    for (int k0 = 0; k0 < 256; k0 += KT) {
        float4 av;
        if (arow < M) {
            av = *(const float4*)&A[(size_t)arow * 256 + k0 + ak];
            if (MODE >= 1) {  // GAT outputs pass through relu before use
                av.x = fmaxf(av.x, 0.f); av.y = fmaxf(av.y, 0.f);
                av.z = fmaxf(av.z, 0.f); av.w = fmaxf(av.w, 0.f);
            }
            if (MODE == 2) {
                float4 av2 = *(const float4*)&A2[(size_t)arow * 256 + k0 + ak];
                av.x = blend0 * av.x + blend1 * fmaxf(av2.x, 0.f);
                av.y = blend0 * av.y + blend1 * fmaxf(av2.y, 0.f);
                av.z = blend0 * av.z + blend1 * fmaxf(av2.z, 0.f);
                av.w = blend0 * av.w + blend1 * fmaxf(av2.w, 0.f);
            }
        } else {
            av = make_float4(0.f, 0.f, 0.f, 0.f);
        }
        As[ak + 0][ar] = av.x; As[ak + 1][ar] = av.y;
        As[ak + 2][ar] = av.z; As[ak + 3][ar] = av.w;
        *(float4*)&Bs[bkk][bc] = *(const float4*)&B[(size_t)(k0 + bkk) * 256 + col0 + bc];
        __syncthreads();
#pragma unroll
        for (int kk = 0; kk < KT; ++kk) {
            float4 a4 = *(const float4*)&As[kk][ty << 2];
            float4 b4 = *(const float4*)&Bs[kk][tx << 2];
            acc[0][0] += a4.x * b4.x; acc[0][1] += a4.x * b4.y; acc[0][2] += a4.x * b4.z; acc[0][3] += a4.x * b4.w;
            acc[1][0] += a4.y * b4.x; acc[1][1] += a4.y * b4.y; acc[1][2] += a4.y * b4.z; acc[1][3] += a4.y * b4.w;
            acc[2][0] += a4.z * b4.x; acc[2][1] += a4.z * b4.y; acc[2][2] += a4.z * b4.z; acc[2][3] += a4.z * b4.w;
            acc[3][0] += a4.w * b4.x; acc[3][1] += a4.w * b4.y; acc[3][2] += a4.w * b4.z; acc[3][3] += a4.w * b4.w;
        }
        __syncthreads();
    }

    const int cbase = col0 + (tx << 2);
    if (MODE == 0) {
        float4 b4 = *(const float4*)&bias[cbase];
#pragma unroll
        for (int i = 0; i < 4; ++i) {
            int r = row0 + (ty << 2) + i;
            if (r < M) {
                float4 v;
                v.x = acc[i][0] + b4.x; v.y = acc[i][1] + b4.y;
                v.z = acc[i][2] + b4.z; v.w = acc[i][3] + b4.w;
                *(float4*)&out[(size_t)r * 256 + cbase] = v;
            }
        }
    } else if (MODE == 1) {
        float4 b4 = *(const float4*)&bias[cbase];
        float4 q4 = *(const float4*)&vq[cbase];
        float p = 0.f;
#pragma unroll
        for (int i = 0; i < 4; ++i) {
            int r = row0 + (ty << 2) + i;
            if (r < M) {
                p += q4.x * tanhf(acc[i][0] + b4.x);
                p += q4.y * tanhf(acc[i][1] + b4.y);
                p += q4.z * tanhf(acc[i][2] + b4.z);
                p += q4.w * tanhf(acc[i][3] + b4.w);
            }
        }
#pragma unroll
        for (int off = 32; off > 0; off >>= 1) p += __shfl_xor(p, off);
        if ((t & 63) == 0) red[t >> 6] = p;
        __syncthreads();
        if (t == 0) atomicAdd(scoreSlot, red[0] + red[1] + red[2] + red[3]);
    } else { // MODE 2
        float4 b4 = *(const float4*)&bias[cbase];
        float4 w4 = *(const float4*)&vq[cbase];
#pragma unroll
        for (int i = 0; i < 4; ++i) {
            float s = fmaxf(acc[i][0] + b4.x, 0.f) * w4.x
                    + fmaxf(acc[i][1] + b4.y, 0.f) * w4.y
                    + fmaxf(acc[i][2] + b4.z, 0.f) * w4.z
                    + fmaxf(acc[i][3] + b4.w, 0.f) * w4.w;
            red[((ty << 2) + i) * 17 + tx] = s;
        }
        __syncthreads();
        if (t < 64) {
            float s = 0.f;
#pragma unroll
            for (int j = 0; j < 16; ++j) s += red[t * 17 + j];
            int r = row0 + t;
            if (r < M) atomicAdd(&out[r], s);
        }
    }
}

// ---------------- per-node attention logits: o_v[n,h] = dot(x[n,h,:], a_v[h,:]) ----------------
__launch_bounds__(256)
__global__ void node_al(const float* __restrict__ x, int N,
                        const float* __restrict__ a0, const float* __restrict__ a1,
                        const float* __restrict__ a2,
                        float* __restrict__ o0, float* __restrict__ o1, float* __restrict__ o2,
                        int nv)
{
    int wid  = (int)((blockIdx.x * 256 + threadIdx.x) >> 6);
    int lane = threadIdx.x & 63;
    if (wid >= N) return;
    float xv[4];
#pragma unroll
    for (int h = 0; h < 4; ++h) xv[h] = x[(size_t)wid * 256 + h * 64 + lane];
    for (int v = 0; v < nv; ++v) {
        const float* a = (v == 0) ? a0 : (v == 1 ? a1 : a2);
        float* o       = (v == 0) ? o0 : (v == 1 ? o1 : o2);
        float p0 = xv[0] * a[lane];
        float p1 = xv[1] * a[64 + lane];
        float p2 = xv[2] * a[128 + lane];
        float p3 = xv[3] * a[192 + lane];
#pragma unroll
        for (int off = 32; off > 0; off >>= 1) {
            p0 += __shfl_xor(p0, off);
            p1 += __shfl_xor(p1, off);
            p2 += __shfl_xor(p2, off);
            p3 += __shfl_xor(p3, off);
        }
        if (lane == 0) {
            o[(size_t)wid * 4 + 0] = p0;
            o[(size_t)wid * 4 + 1] = p1;
            o[(size_t)wid * 4 + 2] = p2;
            o[(size_t)wid * 4 + 3] = p3;
        }
    }
}

// ---------------- per-edge: leaky_relu logits + segment max ----------------
__launch_bounds__(256)
__global__ void edge_al_max(const float* __restrict__ als, const float* __restrict__ ald,
                            const int* __restrict__ src, const int* __restrict__ dst, int E,
                            float* __restrict__ ale, unsigned* __restrict__ amax)
{
    int e = blockIdx.x * 256 + threadIdx.x;
    if (e >= E) return;
    int s = src[e], d = dst[e];
    float4 a = *(const float4*)&als[(size_t)s * 4];
    float4 b = *(const float4*)&ald[(size_t)d * 4];
    float4 al;
    al.x = a.x + b.x; al.x = (al.x >= 0.f) ? al.x : 0.2f * al.x;
    al.y = a.y + b.y; al.y = (al.y >= 0.f) ? al.y : 0.2f * al.y;
    al.z = a.z + b.z; al.z = (al.z >= 0.f) ? al.z : 0.2f * al.z;
    al.w = a.w + b.w; al.w = (al.w >= 0.f) ? al.w : 0.2f * al.w;
    *(float4*)&ale[(size_t)e * 4] = al;
    atomicMax(&amax[(size_t)d * 4 + 0], fenc(al.x));
    atomicMax(&amax[(size_t)d * 4 + 1], fenc(al.y));
    atomicMax(&amax[(size_t)d * 4 + 2], fenc(al.z));
    atomicMax(&amax[(size_t)d * 4 + 3], fenc(al.w));
}

// ---------------- per-edge: e = exp(al - amax[dst]); denom[dst] += e ----------------
__launch_bounds__(256)
__global__ void edge_exp_denom(float* __restrict__ ale, const unsigned* __restrict__ amax,
                               const int* __restrict__ dst, int E, float* __restrict__ denom)
{
    int e = blockIdx.x * 256 + threadIdx.x;
    if (e >= E) return;
    int d = dst[e];
    float4 al = *(const float4*)&ale[(size_t)e * 4];
    uint4 am = *(const uint4*)&amax[(size_t)d * 4];
    float4 ex;
    ex.x = expf(al.x - fdec(am.x));
    ex.y = expf(al.y - fdec(am.y));
    ex.z = expf(al.z - fdec(am.z));
    ex.w = expf(al.w - fdec(am.w));
    *(float4*)&ale[(size_t)e * 4] = ex;
    atomicAdd(&denom[(size_t)d * 4 + 0], ex.x);
    atomicAdd(&denom[(size_t)d * 4 + 1], ex.y);
    atomicAdd(&denom[(size_t)d * 4 + 2], ex.z);
    atomicAdd(&denom[(size_t)d * 4 + 3], ex.w);
}

// ---------------- CSR build: histogram, hierarchical exclusive scan, slot fill ----------------
__global__ void hist_k(const int* __restrict__ dst, int E, int* __restrict__ deg)
{
    int e = blockIdx.x * 256 + threadIdx.x;
    if (e < E) atomicAdd(&deg[dst[e]], 1);
}

__global__ void scan_bsum(const int* __restrict__ deg, int n, int* __restrict__ part)
{
    __shared__ int sm[SCAN_B];
    int i = blockIdx.x * SCAN_B + threadIdx.x;
    sm[threadIdx.x] = (i < n) ? deg[i] : 0;
    __syncthreads();
    for (int off = SCAN_B / 2; off > 0; off >>= 1) {
        if (threadIdx.x < off) sm[threadIdx.x] += sm[threadIdx.x + off];
        __syncthreads();
    }
    if (threadIdx.x == 0) part[blockIdx.x] = sm[0];
}

__global__ void scan_part(int* __restrict__ part, int nb)
{
    // single block, 1024 threads, Hillis-Steele inclusive -> exclusive (nb <= 1024)
    __shared__ int sm[1024];
    int t = threadIdx.x;
    int v = (t < nb) ? part[t] : 0;
    sm[t] = v;
    __syncthreads();
    for (int off = 1; off < 1024; off <<= 1) {
        int add = (t >= off) ? sm[t - off] : 0;
        __syncthreads();
        sm[t] += add;
        __syncthreads();
    }
    if (t < nb) part[t] = sm[t] - v;   // exclusive
}

__global__ void scan_final(const int* __restrict__ deg, int n, const int* __restrict__ part,
                           int* __restrict__ rowptr, int E)
{
    __shared__ int sm[SCAN_B];
    int t = threadIdx.x;
    int i = blockIdx.x * SCAN_B + t;
    int v = (i < n) ? deg[i] : 0;
    sm[t] = v;
    __syncthreads();
    for (int off = 1; off < SCAN_B; off <<= 1) {
        int add = (t >= off) ? sm[t - off] : 0;
        __syncthreads();
        sm[t] += add;
        __syncthreads();
    }
    if (i < n) rowptr[i] = part[blockIdx.x] + sm[t] - v;
    if (blockIdx.x == 0 && t == 0) rowptr[n] = E;
}

__global__ void fill_csr(const int* __restrict__ dst, int E, const int* __restrict__ rowptr,
                         int* __restrict__ cur, int* __restrict__ csr)
{
    int e = blockIdx.x * 256 + threadIdx.x;
    if (e >= E) return;
    int d = dst[e];
    int slot = atomicAdd(&cur[d], 1);
    csr[rowptr[d] + slot] = e;
}

// ---------------- per-dst gather: out[d] = (sum_e exp_e * x_src[src_e]) / denom[d] ----------------
// one wave per dst node; lane owns 4 contiguous dims (float4); head = lane>>4
__launch_bounds__(256)
__global__ void gat_gather(const float* __restrict__ xsrc, const float* __restrict__ ale,
                           const float* __restrict__ denom,
                           const int* __restrict__ rowptr, const int* __restrict__ csr,
                           const int* __restrict__ src, int N, float* __restrict__ outb)
{
    int w    = (int)((blockIdx.x * 256 + threadIdx.x) >> 6);
    int lane = threadIdx.x & 63;
    if (w >= N) return;
    int beg = rowptr[w], end = rowptr[w + 1];
    int h = lane >> 4;
    float4 acc = make_float4(0.f, 0.f, 0.f, 0.f);
    for (int i = beg; i < end; ++i) {
        int e = csr[i];
        int s = src[e];
        float wgt = ale[(size_t)e * 4 + h];
        float4 x = *(const float4*)&xsrc[(size_t)s * 256 + (lane << 2)];
        acc.x += wgt * x.x; acc.y += wgt * x.y;
        acc.z += wgt * x.z; acc.w += wgt * x.w;
    }
    float inv = 1.f / (denom[(size_t)w * 4 + h] + 1e-16f);
    acc.x *= inv; acc.y *= inv; acc.z *= inv; acc.w *= inv;
    *(float4*)&outb[(size_t)w * 256 + (lane << 2)] = acc;
}

__global__ void attn_k(const float* __restrict__ score, float* __restrict__ attn, float invN)
{
    if (threadIdx.x == 0 && blockIdx.x == 0) {
        float s0 = score[0] * invN, s1 = score[1] * invN;
        float m  = fmaxf(s0, s1);
        float e0 = expf(s0 - m), e1 = expf(s1 - m);
        float dsum = e0 + e1;
        attn[0] = e0 / dsum;
        attn[1] = e1 / dsum;
    }
}

__global__ void fill_out(float* __restrict__ o, const float* __restrict__ b2, int n)
{
    int i = blockIdx.x * 256 + threadIdx.x;
    if (i < n) o[i] = b2[0];
}

extern "C" void kernel_launch(void* const* d_in, const int* in_sizes, int n_in,
                              void* d_out, int out_size, void* d_ws, size_t ws_size,
                              hipStream_t stream)
{
    const float* x_job    = (const float*)d_in[0];
    const float* x_skill  = (const float*)d_in[1];
    const float* W_job    = (const float*)d_in[2];
    const float* b_job    = (const float*)d_in[3];
    const float* W_skill  = (const float*)d_in[4];
    const float* b_skill  = (const float*)d_in[5];
    const float* a_src_sj = (const float*)d_in[6];
    const float* a_dst_sj = (const float*)d_in[7];
    const float* a_src_jj = (const float*)d_in[8];
    const float* a_dst_jj = (const float*)d_in[9];
    // d_in[10], d_in[11]: a_src_js / a_dst_js — js edge type's output is unused by the head; skipped.
    const float* q_vec = (const float*)d_in[12];
    const float* Wk    = (const float*)d_in[13];
    const float* bk    = (const float*)d_in[14];
    const float* W1    = (const float*)d_in[15];
    const float* b1    = (const float*)d_in[16];
    const float* W2    = (const float*)d_in[17];
    const float* b2    = (const float*)d_in[18];
    const int* ei_sj_src = (const int*)d_in[19];
    const int* ei_sj_dst = (const int*)d_in[20];
    const int* ei_jj_src = (const int*)d_in[21];
    const int* ei_jj_dst = (const int*)d_in[22];

    const int NJ   = in_sizes[0] / 256;
    const int NS   = in_sizes[1] / 256;
    const int E_sj = in_sizes[19];
    const int E_jj = in_sizes[21];

    char* ws   = (char*)d_ws;
    size_t off = 0;
    auto alloc = [&](size_t bytes) { void* p = ws + off; off += (bytes + 255) & ~(size_t)255; return p; };
    float* h_job   = (float*)alloc((size_t)NJ * 256 * 4);
    float* h_skill = (float*)alloc((size_t)NS * 256 * 4);
    float* out_sj  = (float*)alloc((size_t)NJ * 256 * 4);
    float* out_jj  = (float*)alloc((size_t)NJ * 256 * 4);
    float* ald_sj  = (float*)alloc((size_t)NJ * 4 * 4);
    float* als_jj  = (float*)alloc((size_t)NJ * 4 * 4);
    float* ald_jj  = (float*)alloc((size_t)NJ * 4 * 4);
    float* als_sj  = (float*)alloc((size_t)NS * 4 * 4);
    unsigned* amax_sj = (unsigned*)alloc((size_t)NJ * 4 * 4);
    unsigned* amax_jj = (unsigned*)alloc((size_t)NJ * 4 * 4);
    float* den_sj = (float*)alloc((size_t)NJ * 4 * 4);
    float* den_jj = (float*)alloc((size_t)NJ * 4 * 4);
    float* ale_sj = (float*)alloc((size_t)E_sj * 4 * 4);
    float* ale_jj = (float*)alloc((size_t)E_jj * 4 * 4);
    float* score  = (float*)alloc(64 * 4);   // [0..1] raw scores, [2..3] attn
    float* attn   = score + 2;
    // CSR workspace
    int* deg_sj = (int*)alloc((size_t)NJ * 4);
    int* deg_jj = (int*)alloc((size_t)NJ * 4);
    int* rp_sj  = (int*)alloc(((size_t)NJ + 1) * 4);
    int* rp_jj  = (int*)alloc(((size_t)NJ + 1) * 4);
    int* part_a = (int*)alloc(1024 * 4);
    int* part_b = (int*)alloc(1024 * 4);
    int* cur_sj = (int*)alloc((size_t)NJ * 4);
    int* cur_jj = (int*)alloc((size_t)NJ * 4);
    int* csr_sj = (int*)alloc((size_t)E_sj * 4);
    int* csr_jj = (int*)alloc((size_t)E_jj * 4);
    (void)ws_size; (void)n_in;

    // zero accumulators (fresh every call — timed replays don't re-poison)
    hipMemsetAsync(amax_sj, 0, (size_t)NJ * 4 * 4, stream);
    hipMemsetAsync(amax_jj, 0, (size_t)NJ * 4 * 4, stream);
    hipMemsetAsync(den_sj,  0, (size_t)NJ * 4 * 4, stream);
    hipMemsetAsync(den_jj,  0, (size_t)NJ * 4 * 4, stream);
    hipMemsetAsync(score,   0, 2 * 4, stream);
    hipMemsetAsync(deg_sj,  0, (size_t)NJ * 4, stream);
    hipMemsetAsync(deg_jj,  0, (size_t)NJ * 4, stream);
    hipMemsetAsync(cur_sj,  0, (size_t)NJ * 4, stream);
    hipMemsetAsync(cur_jj,  0, (size_t)NJ * 4, stream);

    dim3 blk(256);
    int gmJ = (NJ + TS - 1) / TS, gmS = (NS + TS - 1) / TS;
    int nbJ = (NJ + SCAN_B - 1) / SCAN_B;   // scan blocks over NJ (<=1024 required for scan_part)

    // ---- CSR build for both edge types (independent of GEMM results) ----
    hist_k<<<dim3((E_sj + 255) / 256), blk, 0, stream>>>(ei_sj_dst, E_sj, deg_sj);
    hist_k<<<dim3((E_jj + 255) / 256), blk, 0, stream>>>(ei_jj_dst, E_jj, deg_jj);
    scan_bsum<<<dim3(nbJ), dim3(SCAN_B), 0, stream>>>(deg_sj, NJ, part_a);
    scan_bsum<<<dim3(nbJ), dim3(SCAN_B), 0, stream>>>(deg_jj, NJ, part_b);
    scan_part<<<dim3(1), dim3(1024), 0, stream>>>(part_a, nbJ);
    scan_part<<<dim3(1), dim3(1024), 0, stream>>>(part_b, nbJ);
    scan_final<<<dim3(nbJ), dim3(SCAN_B), 0, stream>>>(deg_sj, NJ, part_a, rp_sj, E_sj);
    scan_final<<<dim3(nbJ), dim3(SCAN_B), 0, stream>>>(deg_jj, NJ, part_b, rp_jj, E_jj);
    fill_csr<<<dim3((E_sj + 255) / 256), blk, 0, stream>>>(ei_sj_dst, E_sj, rp_sj, cur_sj, csr_sj);
    fill_csr<<<dim3((E_jj + 255) / 256), blk, 0, stream>>>(ei_jj_dst, E_jj, rp_jj, cur_jj, csr_jj);

    // ---- input projections ----
    gemm64<0><<<dim3(gmJ, 4), blk, 0, stream>>>(x_job, nullptr, W_job, b_job,
                                                nullptr, nullptr, h_job, nullptr, NJ);
    gemm64<0><<<dim3(gmS, 4), blk, 0, stream>>>(x_skill, nullptr, W_skill, b_skill,
                                                nullptr, nullptr, h_skill, nullptr, NS);

    // ---- node-level attention logits ----
    node_al<<<dim3((NJ * 64 + 255) / 256), blk, 0, stream>>>(
        h_job, NJ, a_dst_sj, a_src_jj, a_dst_jj, ald_sj, als_jj, ald_jj, 3);
    node_al<<<dim3((NS * 64 + 255) / 256), blk, 0, stream>>>(
        h_skill, NS, a_src_sj, nullptr, nullptr, als_sj, nullptr, nullptr, 1);

    // ---- edge logits: leaky-relu + segment max, then exp + denom ----
    edge_al_max<<<dim3((E_sj + 255) / 256), blk, 0, stream>>>(
        als_sj, ald_sj, ei_sj_src, ei_sj_dst, E_sj, ale_sj, amax_sj);
    edge_al_max<<<dim3((E_jj + 255) / 256), blk, 0, stream>>>(
        als_jj, ald_jj, ei_jj_src, ei_jj_dst, E_jj, ale_jj, amax_jj);
    edge_exp_denom<<<dim3((E_sj + 255) / 256), blk, 0, stream>>>(
        ale_sj, amax_sj, ei_sj_dst, E_sj, den_sj);
    edge_exp_denom<<<dim3((E_jj + 255) / 256), blk, 0, stream>>>(
        ale_jj, amax_jj, ei_jj_dst, E_jj, den_jj);

    // ---- per-dst gather (replaces atomic scatter; writes every row) ----
    gat_gather<<<dim3((NJ + 3) / 4), blk, 0, stream>>>(
        h_skill, ale_sj, den_sj, rp_sj, csr_sj, ei_sj_src, NJ, out_sj);
    gat_gather<<<dim3((NJ + 3) / 4), blk, 0, stream>>>(
        h_job, ale_jj, den_jj, rp_jj, csr_jj, ei_jj_src, NJ, out_jj);

    // ---- semantic attention scores (fused GEMM + relu(A) + tanh + q-dot + sum) ----
    gemm64<1><<<dim3(gmJ, 4), blk, 0, stream>>>(out_sj, nullptr, Wk, bk,
                                                q_vec, nullptr, nullptr, &score[0], NJ);
    gemm64<1><<<dim3(gmJ, 4), blk, 0, stream>>>(out_jj, nullptr, Wk, bk,
                                                q_vec, nullptr, nullptr, &score[1], NJ);

    attn_k<<<1, 64, 0, stream>>>(score, attn, 1.0f / (float)NJ);

    // ---- head: out = relu((attn0*relu(out_sj) + attn1*relu(out_jj)) @ W1 + b1) @ W2 + b2 ----
    fill_out<<<dim3((out_size + 255) / 256), blk, 0, stream>>>((float*)d_out, b2, out_size);
    gemm64<2><<<dim3(gmJ, 4), blk, 0, stream>>>(out_sj, out_jj, W1, b1,
                                                W2, attn, (float*)d_out, nullptr, NJ);
}

// Round 5
// 1036.102 us; speedup vs baseline: 4.4741x; 1.5844x over previous
//
#include <hip/hip_runtime.h>
#include <hip/hip_bf16.h>
#include <math.h>

#define SCAN_B 256

typedef __attribute__((ext_vector_type(8))) short bf16x8;   // 8 bf16 = 4 VGPR
typedef __attribute__((ext_vector_type(4))) float f32x4;

// ---- monotonic float<->uint encoding for atomicMax-based segment_max ----
__device__ __forceinline__ unsigned fenc(float f) {
    unsigned u = __float_as_uint(f);
    return (u & 0x80000000u) ? ~u : (u | 0x80000000u);
}
__device__ __forceinline__ float fdec(unsigned u) {
    return (u & 0x80000000u) ? __uint_as_float(u & 0x7FFFFFFFu) : __uint_as_float(~u);
}
__device__ __forceinline__ unsigned short f2bf(float f) {
    __hip_bfloat16 h = __float2bfloat16(f);   // RNE
    return *(unsigned short*)&h;
}
__device__ __forceinline__ float bf2f(unsigned short u) {
    unsigned v = ((unsigned)u) << 16;
    return __uint_as_float(v);
}

// =============== MFMA GEMM: A[Mpad,256]bf16 @ B^T[256n,256k]bf16 ===============
// 128x256 tile per block (BN=256 = full width -> A fetched once), BK=64,
// 512 thr = 8 waves (2 row x 4 col of 64x64), mfma_f32_16x16x32_bf16.
// MODE 0: out[M,256] = A@B + bias                      (f32 out)
// MODE 1: atomicAdd(scoreSlot, sum_{rows<M} q . tanh(A@B + bias))
// MODE 2: out[row] = sum_j relu((A@B)[row,j]+bias[j]) * vq[j] + b2p[0]
//         (per-wave 64-col partials -> LDS -> cross-wave sum; NO races)
template<int MODE>
__launch_bounds__(512)
__global__ void gemm_mfma(const unsigned short* __restrict__ Abf,
                          const unsigned short* __restrict__ Bt,
                          const float* __restrict__ bias,
                          const float* __restrict__ vq,
                          const float* __restrict__ b2p,
                          float* __restrict__ out,
                          float* __restrict__ scoreSlot, int M)
{
    __shared__ __align__(16) char sm[49152];   // A: [0,16K) = [128][64]bf16; B^T: [16K,48K) = [256][64]bf16
    __shared__ float red8[8];
    const int t    = threadIdx.x;
    const int lane = t & 63, wid = t >> 6;
    const int wr = wid >> 2, wc = wid & 3;
    const long row0 = (long)blockIdx.x * 128;
    const char* Ab = (const char*)Abf;
    const char* Bb = (const char*)Bt;

    f32x4 acc[4][4];
#pragma unroll
    for (int m = 0; m < 4; ++m)
#pragma unroll
        for (int n = 0; n < 4; ++n) acc[m][n] = (f32x4){0.f, 0.f, 0.f, 0.f};

    for (int k0 = 0; k0 < 256; k0 += 64) {
        // ---- stage A tile (16 KB): linear global read, XOR-swizzled LDS write ----
#pragma unroll
        for (int rep = 0; rep < 2; ++rep) {
            int idx = rep * 512 + t;
            int row = idx >> 3, colb = (idx & 7) << 4;
            uint4 v = *(const uint4*)(Ab + (row0 + row) * 512 + k0 * 2 + colb);
            *(uint4*)&sm[row * 128 + (colb ^ ((row & 7) << 4))] = v;
        }
        // ---- stage B^T tile (32 KB) ----
#pragma unroll
        for (int rep = 0; rep < 4; ++rep) {
            int idx = rep * 512 + t;
            int n = idx >> 3, colb = (idx & 7) << 4;
            uint4 v = *(const uint4*)(Bb + n * 512 + k0 * 2 + colb);
            *(uint4*)&sm[16384 + n * 128 + (colb ^ ((n & 7) << 4))] = v;
        }
        __syncthreads();
#pragma unroll
        for (int kki = 0; kki < 2; ++kki) {
            const int kb = kki * 64 + ((lane >> 4) << 4);
            bf16x8 a[4], b[4];
#pragma unroll
            for (int m = 0; m < 4; ++m) {
                int row = wr * 64 + m * 16 + (lane & 15);
                a[m] = *(const bf16x8*)&sm[row * 128 + (kb ^ ((row & 7) << 4))];
            }
#pragma unroll
            for (int n = 0; n < 4; ++n) {
                int nr = wc * 64 + n * 16 + (lane & 15);
                b[n] = *(const bf16x8*)&sm[16384 + nr * 128 + (kb ^ ((nr & 7) << 4))];
            }
#pragma unroll
            for (int m = 0; m < 4; ++m)
#pragma unroll
                for (int n = 0; n < 4; ++n)
                    acc[m][n] = __builtin_amdgcn_mfma_f32_16x16x32_bf16(a[m], b[n], acc[m][n], 0, 0, 0);
        }
        __syncthreads();
    }

    const int colbase = wc * 64 + (lane & 15);
    const int rbase   = wr * 64 + ((lane >> 4) << 2);
    if (MODE == 0) {
#pragma unroll
        for (int n = 0; n < 4; ++n) {
            int col = colbase + n * 16;
            float bv = bias[col];
#pragma unroll
            for (int m = 0; m < 4; ++m) {
                long row = row0 + rbase + m * 16;
#pragma unroll
                for (int j = 0; j < 4; ++j)
                    if (row + j < M) out[(row + j) * 256 + col] = acc[m][n][j] + bv;
            }
        }
    } else if (MODE == 1) {
        float p = 0.f;
#pragma unroll
        for (int n = 0; n < 4; ++n) {
            int col = colbase + n * 16;
            float bv = bias[col], qv = vq[col];
#pragma unroll
            for (int m = 0; m < 4; ++m) {
                long row = row0 + rbase + m * 16;
#pragma unroll
                for (int j = 0; j < 4; ++j)
                    if (row + j < M) p += qv * tanhf(acc[m][n][j] + bv);
            }
        }
#pragma unroll
        for (int off = 32; off > 0; off >>= 1) p += __shfl_xor(p, off);
        if (lane == 0) red8[wid] = p;
        __syncthreads();
        if (t == 0) {
            float s = 0.f;
#pragma unroll
            for (int i = 0; i < 8; ++i) s += red8[i];
            atomicAdd(scoreSlot, s);
        }
    } else {
        // MODE 2: each wave's lanes cover 64 cols; reduce within 16-lane group,
        // park per-wave partial in LDS[localrow][wc], then cross-wave sum.
        float* redC = (float*)sm;   // reuse tile buffer (free after final barrier)
        float b2v = b2p[0];
        float bv[4], wv[4];
#pragma unroll
        for (int n = 0; n < 4; ++n) {
            int col = colbase + n * 16;
            bv[n] = bias[col]; wv[n] = vq[col];
        }
#pragma unroll
        for (int m = 0; m < 4; ++m) {
#pragma unroll
            for (int j = 0; j < 4; ++j) {
                float s = 0.f;
#pragma unroll
                for (int n = 0; n < 4; ++n)
                    s += fmaxf(acc[m][n][j] + bv[n], 0.f) * wv[n];
                s += __shfl_xor(s, 1); s += __shfl_xor(s, 2);
                s += __shfl_xor(s, 4); s += __shfl_xor(s, 8);
                if ((lane & 15) == 0) {
                    int lrow = wr * 64 + m * 16 + ((lane >> 4) << 2) + j;
                    redC[lrow * 4 + wc] = s;
                }
            }
        }
        __syncthreads();
        if (t < 128) {
            long row = row0 + t;
            if (row < M)
                out[row] = redC[t * 4 + 0] + redC[t * 4 + 1]
                         + redC[t * 4 + 2] + redC[t * 4 + 3] + b2v;
        }
    }
}

// ---------------- casts / transposes / blend ----------------
__global__ void cast_pad(const float* __restrict__ src, unsigned short* __restrict__ dst,
                         long n, long npad)
{
    long i = ((long)blockIdx.x * 256 + threadIdx.x) * 4;
    if (i >= npad) return;
    ushort4 o;
    if (i + 4 <= n) {
        float4 v = *(const float4*)&src[i];
        o.x = f2bf(v.x); o.y = f2bf(v.y); o.z = f2bf(v.z); o.w = f2bf(v.w);
    } else {
        float vv[4];
#pragma unroll
        for (int j = 0; j < 4; ++j) vv[j] = (i + j < n) ? src[i + j] : 0.f;
        o.x = f2bf(vv[0]); o.y = f2bf(vv[1]); o.z = f2bf(vv[2]); o.w = f2bf(vv[3]);
    }
    *(ushort4*)&dst[i] = o;
}

__global__ void transpose_cast(const float* __restrict__ W, unsigned short* __restrict__ Wt)
{   // Wt[n][k] = bf16(W[k][n]); 256x256
    int n = blockIdx.x, k = threadIdx.x;
    Wt[n * 256 + k] = f2bf(W[k * 256 + n]);
}

__global__ void blend_k(const unsigned short* __restrict__ a, const unsigned short* __restrict__ b,
                        const float* __restrict__ attn, unsigned short* __restrict__ o, long n)
{
    long i = ((long)blockIdx.x * 256 + threadIdx.x) * 4;
    if (i >= n) return;
    float a0 = attn[0], a1 = attn[1];
    ushort4 ua = *(const ushort4*)&a[i];
    ushort4 ub = *(const ushort4*)&b[i];
    ushort4 uo;
    uo.x = f2bf(a0 * bf2f(ua.x) + a1 * bf2f(ub.x));
    uo.y = f2bf(a0 * bf2f(ua.y) + a1 * bf2f(ub.y));
    uo.z = f2bf(a0 * bf2f(ua.z) + a1 * bf2f(ub.z));
    uo.w = f2bf(a0 * bf2f(ua.w) + a1 * bf2f(ub.w));
    *(ushort4*)&o[i] = uo;
}

// ---------------- per-node attention logits ----------------
__launch_bounds__(256)
__global__ void node_al(const float* __restrict__ x, int N,
                        const float* __restrict__ a0, const float* __restrict__ a1,
                        const float* __restrict__ a2,
                        float* __restrict__ o0, float* __restrict__ o1, float* __restrict__ o2,
                        int nv)
{
    int wid  = (int)((blockIdx.x * 256 + threadIdx.x) >> 6);
    int lane = threadIdx.x & 63;
    if (wid >= N) return;
    float xv[4];
#pragma unroll
    for (int h = 0; h < 4; ++h) xv[h] = x[(size_t)wid * 256 + h * 64 + lane];
    for (int v = 0; v < nv; ++v) {
        const float* a = (v == 0) ? a0 : (v == 1 ? a1 : a2);
        float* o       = (v == 0) ? o0 : (v == 1 ? o1 : o2);
        float p0 = xv[0] * a[lane];
        float p1 = xv[1] * a[64 + lane];
        float p2 = xv[2] * a[128 + lane];
        float p3 = xv[3] * a[192 + lane];
#pragma unroll
        for (int off = 32; off > 0; off >>= 1) {
            p0 += __shfl_xor(p0, off);
            p1 += __shfl_xor(p1, off);
            p2 += __shfl_xor(p2, off);
            p3 += __shfl_xor(p3, off);
        }
        if (lane == 0) {
            o[(size_t)wid * 4 + 0] = p0;
            o[(size_t)wid * 4 + 1] = p1;
            o[(size_t)wid * 4 + 2] = p2;
            o[(size_t)wid * 4 + 3] = p3;
        }
    }
}

// ---------------- per-edge: leaky_relu logits + segment max ----------------
__launch_bounds__(256)
__global__ void edge_al_max(const float* __restrict__ als, const float* __restrict__ ald,
                            const int* __restrict__ src, const int* __restrict__ dst, int E,
                            float* __restrict__ ale, unsigned* __restrict__ amax)
{
    int e = blockIdx.x * 256 + threadIdx.x;
    if (e >= E) return;
    int s = src[e], d = dst[e];
    float4 a = *(const float4*)&als[(size_t)s * 4];
    float4 b = *(const float4*)&ald[(size_t)d * 4];
    float4 al;
    al.x = a.x + b.x; al.x = (al.x >= 0.f) ? al.x : 0.2f * al.x;
    al.y = a.y + b.y; al.y = (al.y >= 0.f) ? al.y : 0.2f * al.y;
    al.z = a.z + b.z; al.z = (al.z >= 0.f) ? al.z : 0.2f * al.z;
    al.w = a.w + b.w; al.w = (al.w >= 0.f) ? al.w : 0.2f * al.w;
    *(float4*)&ale[(size_t)e * 4] = al;
    atomicMax(&amax[(size_t)d * 4 + 0], fenc(al.x));
    atomicMax(&amax[(size_t)d * 4 + 1], fenc(al.y));
    atomicMax(&amax[(size_t)d * 4 + 2], fenc(al.z));
    atomicMax(&amax[(size_t)d * 4 + 3], fenc(al.w));
}

// ---------------- per-edge: e = exp(al - amax[dst]); denom[dst] += e ----------------
__launch_bounds__(256)
__global__ void edge_exp_denom(float* __restrict__ ale, const unsigned* __restrict__ amax,
                               const int* __restrict__ dst, int E, float* __restrict__ denom)
{
    int e = blockIdx.x * 256 + threadIdx.x;
    if (e >= E) return;
    int d = dst[e];
    float4 al = *(const float4*)&ale[(size_t)e * 4];
    uint4 am = *(const uint4*)&amax[(size_t)d * 4];
    float4 ex;
    ex.x = expf(al.x - fdec(am.x));
    ex.y = expf(al.y - fdec(am.y));
    ex.z = expf(al.z - fdec(am.z));
    ex.w = expf(al.w - fdec(am.w));
    *(float4*)&ale[(size_t)e * 4] = ex;
    atomicAdd(&denom[(size_t)d * 4 + 0], ex.x);
    atomicAdd(&denom[(size_t)d * 4 + 1], ex.y);
    atomicAdd(&denom[(size_t)d * 4 + 2], ex.z);
    atomicAdd(&denom[(size_t)d * 4 + 3], ex.w);
}

// ---------------- CSR build ----------------
__global__ void hist_k(const int* __restrict__ dst, int E, int* __restrict__ deg)
{
    int e = blockIdx.x * 256 + threadIdx.x;
    if (e < E) atomicAdd(&deg[dst[e]], 1);
}

__global__ void scan_bsum(const int* __restrict__ deg, int n, int* __restrict__ part)
{
    __shared__ int smem[SCAN_B];
    int i = blockIdx.x * SCAN_B + threadIdx.x;
    smem[threadIdx.x] = (i < n) ? deg[i] : 0;
    __syncthreads();
    for (int off = SCAN_B / 2; off > 0; off >>= 1) {
        if (threadIdx.x < off) smem[threadIdx.x] += smem[threadIdx.x + off];
        __syncthreads();
    }
    if (threadIdx.x == 0) part[blockIdx.x] = smem[0];
}

__global__ void scan_part(int* __restrict__ part, int nb)
{
    __shared__ int smem[1024];
    int t = threadIdx.x;
    int v = (t < nb) ? part[t] : 0;
    smem[t] = v;
    __syncthreads();
    for (int off = 1; off < 1024; off <<= 1) {
        int add = (t >= off) ? smem[t - off] : 0;
        __syncthreads();
        smem[t] += add;
        __syncthreads();
    }
    if (t < nb) part[t] = smem[t] - v;
}

__global__ void scan_final(const int* __restrict__ deg, int n, const int* __restrict__ part,
                           int* __restrict__ rowptr, int E)
{
    __shared__ int smem[SCAN_B];
    int t = threadIdx.x;
    int i = blockIdx.x * SCAN_B + t;
    int v = (i < n) ? deg[i] : 0;
    smem[t] = v;
    __syncthreads();
    for (int off = 1; off < SCAN_B; off <<= 1) {
        int add = (t >= off) ? smem[t - off] : 0;
        __syncthreads();
        smem[t] += add;
        __syncthreads();
    }
    if (i < n) rowptr[i] = part[blockIdx.x] + smem[t] - v;
    if (blockIdx.x == 0 && t == 0) rowptr[n] = E;
}

__global__ void fill_csr(const int* __restrict__ dst, int E, const int* __restrict__ rowptr,
                         int* __restrict__ cur, int* __restrict__ csr)
{
    int e = blockIdx.x * 256 + threadIdx.x;
    if (e >= E) return;
    int d = dst[e];
    int slot = atomicAdd(&cur[d], 1);
    csr[rowptr[d] + slot] = e;
}

// ------- per-dst gather -> relu -> bf16 row (feeds score/head GEMMs) -------
__launch_bounds__(256)
__global__ void gat_gather(const float* __restrict__ xsrc, const float* __restrict__ ale,
                           const float* __restrict__ denom,
                           const int* __restrict__ rowptr, const int* __restrict__ csr,
                           const int* __restrict__ src, int N, unsigned short* __restrict__ outb)
{
    int w    = (int)((blockIdx.x * 256 + threadIdx.x) >> 6);
    int lane = threadIdx.x & 63;
    if (w >= N) return;
    int beg = rowptr[w], end = rowptr[w + 1];
    int h = lane >> 4;
    float4 acc = make_float4(0.f, 0.f, 0.f, 0.f);
    for (int i = beg; i < end; ++i) {
        int e = csr[i];
        int s = src[e];
        float wgt = ale[(size_t)e * 4 + h];
        float4 x = *(const float4*)&xsrc[(size_t)s * 256 + (lane << 2)];
        acc.x += wgt * x.x; acc.y += wgt * x.y;
        acc.z += wgt * x.z; acc.w += wgt * x.w;
    }
    float inv = 1.f / (denom[(size_t)w * 4 + h] + 1e-16f);
    ushort4 uo;
    uo.x = f2bf(fmaxf(acc.x * inv, 0.f));
    uo.y = f2bf(fmaxf(acc.y * inv, 0.f));
    uo.z = f2bf(fmaxf(acc.z * inv, 0.f));
    uo.w = f2bf(fmaxf(acc.w * inv, 0.f));
    *(ushort4*)&outb[(size_t)w * 256 + (lane << 2)] = uo;
}

__global__ void attn_k(const float* __restrict__ score, float* __restrict__ attn, float invN)
{
    if (threadIdx.x == 0 && blockIdx.x == 0) {
        float s0 = score[0] * invN, s1 = score[1] * invN;
        float m  = fmaxf(s0, s1);
        float e0 = expf(s0 - m), e1 = expf(s1 - m);
        float dsum = e0 + e1;
        attn[0] = e0 / dsum;
        attn[1] = e1 / dsum;
    }
}

extern "C" void kernel_launch(void* const* d_in, const int* in_sizes, int n_in,
                              void* d_out, int out_size, void* d_ws, size_t ws_size,
                              hipStream_t stream)
{
    const float* x_job    = (const float*)d_in[0];
    const float* x_skill  = (const float*)d_in[1];
    const float* W_job    = (const float*)d_in[2];
    const float* b_job    = (const float*)d_in[3];
    const float* W_skill  = (const float*)d_in[4];
    const float* b_skill  = (const float*)d_in[5];
    const float* a_src_sj = (const float*)d_in[6];
    const float* a_dst_sj = (const float*)d_in[7];
    const float* a_src_jj = (const float*)d_in[8];
    const float* a_dst_jj = (const float*)d_in[9];
    // d_in[10], d_in[11]: a_src_js / a_dst_js — js edge-type output unused by the head; skipped.
    const float* q_vec = (const float*)d_in[12];
    const float* Wk    = (const float*)d_in[13];
    const float* bk    = (const float*)d_in[14];
    const float* W1    = (const float*)d_in[15];
    const float* b1    = (const float*)d_in[16];
    const float* W2    = (const float*)d_in[17];
    const float* b2    = (const float*)d_in[18];
    const int* ei_sj_src = (const int*)d_in[19];
    const int* ei_sj_dst = (const int*)d_in[20];
    const int* ei_jj_src = (const int*)d_in[21];
    const int* ei_jj_dst = (const int*)d_in[22];

    const int NJ   = in_sizes[0] / 256;
    const int NS   = in_sizes[1] / 256;
    const int E_sj = in_sizes[19];
    const int E_jj = in_sizes[21];
    const int gmJ  = (NJ + 127) / 128, gmS = (NS + 127) / 128;
    const long MpadJ = (long)gmJ * 128, MpadS = (long)gmS * 128;

    char* ws   = (char*)d_ws;
    size_t off = 0;
    auto alloc = [&](size_t bytes) { void* p = ws + off; off += (bytes + 255) & ~(size_t)255; return p; };
    float* h_job   = (float*)alloc(MpadJ * 256 * 4);
    float* h_skill = (float*)alloc(MpadS * 256 * 4);
    unsigned short* x_job_bf   = (unsigned short*)alloc(MpadJ * 256 * 2);
    unsigned short* x_skill_bf = (unsigned short*)alloc(MpadS * 256 * 2);
    unsigned short* Wjob_t  = (unsigned short*)alloc(256 * 256 * 2);
    unsigned short* Wskl_t  = (unsigned short*)alloc(256 * 256 * 2);
    unsigned short* Wk_t    = (unsigned short*)alloc(256 * 256 * 2);
    unsigned short* W1_t    = (unsigned short*)alloc(256 * 256 * 2);
    unsigned short* out_sj_bf = (unsigned short*)alloc(MpadJ * 256 * 2);
    unsigned short* out_jj_bf = (unsigned short*)alloc(MpadJ * 256 * 2);
    unsigned short* ablend = x_job_bf;   // alias: x_job_bf dead after proj GEMM
    float* ald_sj  = (float*)alloc((size_t)NJ * 4 * 4);
    float* als_jj  = (float*)alloc((size_t)NJ * 4 * 4);
    float* ald_jj  = (float*)alloc((size_t)NJ * 4 * 4);
    float* als_sj  = (float*)alloc((size_t)NS * 4 * 4);
    unsigned* amax_sj = (unsigned*)alloc((size_t)NJ * 4 * 4);
    unsigned* amax_jj = (unsigned*)alloc((size_t)NJ * 4 * 4);
    float* den_sj = (float*)alloc((size_t)NJ * 4 * 4);
    float* den_jj = (float*)alloc((size_t)NJ * 4 * 4);
    float* ale_sj = (float*)alloc((size_t)E_sj * 4 * 4);
    float* ale_jj = (float*)alloc((size_t)E_jj * 4 * 4);
    float* score  = (float*)alloc(64 * 4);   // [0..1] raw scores, [2..3] attn
    float* attn   = score + 2;
    int* deg_sj = (int*)alloc((size_t)NJ * 4);
    int* deg_jj = (int*)alloc((size_t)NJ * 4);
    int* rp_sj  = (int*)alloc(((size_t)NJ + 1) * 4);
    int* rp_jj  = (int*)alloc(((size_t)NJ + 1) * 4);
    int* part_a = (int*)alloc(1024 * 4);
    int* part_b = (int*)alloc(1024 * 4);
    int* cur_sj = (int*)alloc((size_t)NJ * 4);
    int* cur_jj = (int*)alloc((size_t)NJ * 4);
    int* csr_sj = (int*)alloc((size_t)E_sj * 4);
    int* csr_jj = (int*)alloc((size_t)E_jj * 4);
    (void)ws_size; (void)n_in;

    hipMemsetAsync(amax_sj, 0, (size_t)NJ * 4 * 4, stream);
    hipMemsetAsync(amax_jj, 0, (size_t)NJ * 4 * 4, stream);
    hipMemsetAsync(den_sj,  0, (size_t)NJ * 4 * 4, stream);
    hipMemsetAsync(den_jj,  0, (size_t)NJ * 4 * 4, stream);
    hipMemsetAsync(score,   0, 2 * 4, stream);
    hipMemsetAsync(deg_sj,  0, (size_t)NJ * 4, stream);
    hipMemsetAsync(deg_jj,  0, (size_t)NJ * 4, stream);
    hipMemsetAsync(cur_sj,  0, (size_t)NJ * 4, stream);
    hipMemsetAsync(cur_jj,  0, (size_t)NJ * 4, stream);

    dim3 blk(256);
    int nbJ = (NJ + SCAN_B - 1) / SCAN_B;

    // ---- casts & weight transposes ----
    long nJ = (long)NJ * 256, nJp = MpadJ * 256;
    long nS = (long)NS * 256, nSp = MpadS * 256;
    cast_pad<<<dim3((int)((nJp / 4 + 255) / 256)), blk, 0, stream>>>(x_job, x_job_bf, nJ, nJp);
    cast_pad<<<dim3((int)((nSp / 4 + 255) / 256)), blk, 0, stream>>>(x_skill, x_skill_bf, nS, nSp);
    transpose_cast<<<dim3(256), blk, 0, stream>>>(W_job, Wjob_t);
    transpose_cast<<<dim3(256), blk, 0, stream>>>(W_skill, Wskl_t);
    transpose_cast<<<dim3(256), blk, 0, stream>>>(Wk, Wk_t);
    transpose_cast<<<dim3(256), blk, 0, stream>>>(W1, W1_t);

    // ---- CSR build ----
    hist_k<<<dim3((E_sj + 255) / 256), blk, 0, stream>>>(ei_sj_dst, E_sj, deg_sj);
    hist_k<<<dim3((E_jj + 255) / 256), blk, 0, stream>>>(ei_jj_dst, E_jj, deg_jj);
    scan_bsum<<<dim3(nbJ), dim3(SCAN_B), 0, stream>>>(deg_sj, NJ, part_a);
    scan_bsum<<<dim3(nbJ), dim3(SCAN_B), 0, stream>>>(deg_jj, NJ, part_b);
    scan_part<<<dim3(1), dim3(1024), 0, stream>>>(part_a, nbJ);
    scan_part<<<dim3(1), dim3(1024), 0, stream>>>(part_b, nbJ);
    scan_final<<<dim3(nbJ), dim3(SCAN_B), 0, stream>>>(deg_sj, NJ, part_a, rp_sj, E_sj);
    scan_final<<<dim3(nbJ), dim3(SCAN_B), 0, stream>>>(deg_jj, NJ, part_b, rp_jj, E_jj);
    fill_csr<<<dim3((E_sj + 255) / 256), blk, 0, stream>>>(ei_sj_dst, E_sj, rp_sj, cur_sj, csr_sj);
    fill_csr<<<dim3((E_jj + 255) / 256), blk, 0, stream>>>(ei_jj_dst, E_jj, rp_jj, cur_jj, csr_jj);

    // ---- input projections (MFMA) ----
    gemm_mfma<0><<<dim3(gmJ), dim3(512), 0, stream>>>(x_job_bf, Wjob_t, b_job,
                                                      nullptr, nullptr, h_job, nullptr, NJ);
    gemm_mfma<0><<<dim3(gmS), dim3(512), 0, stream>>>(x_skill_bf, Wskl_t, b_skill,
                                                      nullptr, nullptr, h_skill, nullptr, NS);

    // ---- node-level attention logits ----
    node_al<<<dim3((NJ * 64 + 255) / 256), blk, 0, stream>>>(
        h_job, NJ, a_dst_sj, a_src_jj, a_dst_jj, ald_sj, als_jj, ald_jj, 3);
    node_al<<<dim3((NS * 64 + 255) / 256), blk, 0, stream>>>(
        h_skill, NS, a_src_sj, nullptr, nullptr, als_sj, nullptr, nullptr, 1);

    // ---- edge logits + softmax pieces ----
    edge_al_max<<<dim3((E_sj + 255) / 256), blk, 0, stream>>>(
        als_sj, ald_sj, ei_sj_src, ei_sj_dst, E_sj, ale_sj, amax_sj);
    edge_al_max<<<dim3((E_jj + 255) / 256), blk, 0, stream>>>(
        als_jj, ald_jj, ei_jj_src, ei_jj_dst, E_jj, ale_jj, amax_jj);
    edge_exp_denom<<<dim3((E_sj + 255) / 256), blk, 0, stream>>>(
        ale_sj, amax_sj, ei_sj_dst, E_sj, den_sj);
    edge_exp_denom<<<dim3((E_jj + 255) / 256), blk, 0, stream>>>(
        ale_jj, amax_jj, ei_jj_dst, E_jj, den_jj);

    // ---- per-dst gather -> relu -> bf16 ----
    gat_gather<<<dim3((NJ + 3) / 4), blk, 0, stream>>>(
        h_skill, ale_sj, den_sj, rp_sj, csr_sj, ei_sj_src, NJ, out_sj_bf);
    gat_gather<<<dim3((NJ + 3) / 4), blk, 0, stream>>>(
        h_job, ale_jj, den_jj, rp_jj, csr_jj, ei_jj_src, NJ, out_jj_bf);

    // ---- semantic attention scores (MFMA, fused tanh + q-dot + sum) ----
    gemm_mfma<1><<<dim3(gmJ), dim3(512), 0, stream>>>(out_sj_bf, Wk_t, bk,
                                                      q_vec, nullptr, nullptr, &score[0], NJ);
    gemm_mfma<1><<<dim3(gmJ), dim3(512), 0, stream>>>(out_jj_bf, Wk_t, bk,
                                                      q_vec, nullptr, nullptr, &score[1], NJ);
    attn_k<<<1, 64, 0, stream>>>(score, attn, 1.0f / (float)NJ);

    // ---- blend (bf16) then head (MFMA, fused relu + W2-dot + b2) ----
    blend_k<<<dim3((int)((nJ / 4 + 255) / 256)), blk, 0, stream>>>(
        out_sj_bf, out_jj_bf, attn, ablend, nJ);
    gemm_mfma<2><<<dim3(gmJ), dim3(512), 0, stream>>>(ablend, W1_t, b1,
                                                      W2, b2, (float*)d_out, nullptr, NJ);
}

// Round 6
// 656.503 us; speedup vs baseline: 7.0610x; 1.5782x over previous
//
#include <hip/hip_runtime.h>
#include <hip/hip_bf16.h>
#include <math.h>

#define SCAN_B 256
#define NEG_BIG (-3.0e38f)

typedef __attribute__((ext_vector_type(8))) short bf16x8;   // 8 bf16 = 4 VGPR
typedef __attribute__((ext_vector_type(4))) float f32x4;

__device__ __forceinline__ unsigned short f2bf(float f) {
    __hip_bfloat16 h = __float2bfloat16(f);   // RNE
    return *(unsigned short*)&h;
}
__device__ __forceinline__ float bf2f(unsigned short u) {
    unsigned v = ((unsigned)u) << 16;
    return __uint_as_float(v);
}
__device__ __forceinline__ float lrelu(float x) { return (x >= 0.f) ? x : 0.2f * x; }

// =============== MFMA GEMM: A[Mpad,256]bf16 @ B^T[256n,256k]bf16 ===============
// 128x256 tile per block (BN=256 = full width -> A fetched once), BK=64,
// 512 thr = 8 waves (2 row x 4 col of 64x64), mfma_f32_16x16x32_bf16.
// MODE 0: out[M,256] = A@B + bias                      (f32 out)
// MODE 1: atomicAdd(scoreSlot, sum_{rows<M} q . tanh(A@B + bias))
// MODE 2: out[row] = sum_j relu((A@B)[row,j]+bias[j]) * vq[j] + b2p[0]
//         (per-wave 64-col partials -> LDS -> cross-wave sum)
template<int MODE>
__launch_bounds__(512)
__global__ void gemm_mfma(const unsigned short* __restrict__ Abf,
                          const unsigned short* __restrict__ Bt,
                          const float* __restrict__ bias,
                          const float* __restrict__ vq,
                          const float* __restrict__ b2p,
                          float* __restrict__ out,
                          float* __restrict__ scoreSlot, int M)
{
    __shared__ __align__(16) char sm[49152];   // A: [0,16K) = [128][64]bf16; B^T: [16K,48K) = [256][64]bf16
    __shared__ float red8[8];
    const int t    = threadIdx.x;
    const int lane = t & 63, wid = t >> 6;
    const int wr = wid >> 2, wc = wid & 3;
    const long row0 = (long)blockIdx.x * 128;
    const char* Ab = (const char*)Abf;
    const char* Bb = (const char*)Bt;

    f32x4 acc[4][4];
#pragma unroll
    for (int m = 0; m < 4; ++m)
#pragma unroll
        for (int n = 0; n < 4; ++n) acc[m][n] = (f32x4){0.f, 0.f, 0.f, 0.f};

    for (int k0 = 0; k0 < 256; k0 += 64) {
#pragma unroll
        for (int rep = 0; rep < 2; ++rep) {
            int idx = rep * 512 + t;
            int row = idx >> 3, colb = (idx & 7) << 4;
            uint4 v = *(const uint4*)(Ab + (row0 + row) * 512 + k0 * 2 + colb);
            *(uint4*)&sm[row * 128 + (colb ^ ((row & 7) << 4))] = v;
        }
#pragma unroll
        for (int rep = 0; rep < 4; ++rep) {
            int idx = rep * 512 + t;
            int n = idx >> 3, colb = (idx & 7) << 4;
            uint4 v = *(const uint4*)(Bb + n * 512 + k0 * 2 + colb);
            *(uint4*)&sm[16384 + n * 128 + (colb ^ ((n & 7) << 4))] = v;
        }
        __syncthreads();
#pragma unroll
        for (int kki = 0; kki < 2; ++kki) {
            const int kb = kki * 64 + ((lane >> 4) << 4);
            bf16x8 a[4], b[4];
#pragma unroll
            for (int m = 0; m < 4; ++m) {
                int row = wr * 64 + m * 16 + (lane & 15);
                a[m] = *(const bf16x8*)&sm[row * 128 + (kb ^ ((row & 7) << 4))];
            }
#pragma unroll
            for (int n = 0; n < 4; ++n) {
                int nr = wc * 64 + n * 16 + (lane & 15);
                b[n] = *(const bf16x8*)&sm[16384 + nr * 128 + (kb ^ ((nr & 7) << 4))];
            }
#pragma unroll
            for (int m = 0; m < 4; ++m)
#pragma unroll
                for (int n = 0; n < 4; ++n)
                    acc[m][n] = __builtin_amdgcn_mfma_f32_16x16x32_bf16(a[m], b[n], acc[m][n], 0, 0, 0);
        }
        __syncthreads();
    }

    const int colbase = wc * 64 + (lane & 15);
    const int rbase   = wr * 64 + ((lane >> 4) << 2);
    if (MODE == 0) {
#pragma unroll
        for (int n = 0; n < 4; ++n) {
            int col = colbase + n * 16;
            float bv = bias[col];
#pragma unroll
            for (int m = 0; m < 4; ++m) {
                long row = row0 + rbase + m * 16;
#pragma unroll
                for (int j = 0; j < 4; ++j)
                    if (row + j < M) out[(row + j) * 256 + col] = acc[m][n][j] + bv;
            }
        }
    } else if (MODE == 1) {
        float p = 0.f;
#pragma unroll
        for (int n = 0; n < 4; ++n) {
            int col = colbase + n * 16;
            float bv = bias[col], qv = vq[col];
#pragma unroll
            for (int m = 0; m < 4; ++m) {
                long row = row0 + rbase + m * 16;
#pragma unroll
                for (int j = 0; j < 4; ++j)
                    if (row + j < M) p += qv * tanhf(acc[m][n][j] + bv);
            }
        }
#pragma unroll
        for (int off = 32; off > 0; off >>= 1) p += __shfl_xor(p, off);
        if (lane == 0) red8[wid] = p;
        __syncthreads();
        if (t == 0) {
            float s = 0.f;
#pragma unroll
            for (int i = 0; i < 8; ++i) s += red8[i];
            atomicAdd(scoreSlot, s);
        }
    } else {
        float* redC = (float*)sm;   // reuse tile buffer (free after final barrier)
        float b2v = b2p[0];
        float bv[4], wv[4];
#pragma unroll
        for (int n = 0; n < 4; ++n) {
            int col = colbase + n * 16;
            bv[n] = bias[col]; wv[n] = vq[col];
        }
#pragma unroll
        for (int m = 0; m < 4; ++m) {
#pragma unroll
            for (int j = 0; j < 4; ++j) {
                float s = 0.f;
#pragma unroll
                for (int n = 0; n < 4; ++n)
                    s += fmaxf(acc[m][n][j] + bv[n], 0.f) * wv[n];
                s += __shfl_xor(s, 1); s += __shfl_xor(s, 2);
                s += __shfl_xor(s, 4); s += __shfl_xor(s, 8);
                if ((lane & 15) == 0) {
                    int lrow = wr * 64 + m * 16 + ((lane >> 4) << 2) + j;
                    redC[lrow * 4 + wc] = s;
                }
            }
        }
        __syncthreads();
        if (t < 128) {
            long row = row0 + t;
            if (row < M)
                out[row] = redC[t * 4 + 0] + redC[t * 4 + 1]
                         + redC[t * 4 + 2] + redC[t * 4 + 3] + b2v;
        }
    }
}

// ---------------- casts / transposes / blend ----------------
__global__ void cast_pad(const float* __restrict__ src, unsigned short* __restrict__ dst,
                         long n, long npad)
{
    long i = ((long)blockIdx.x * 256 + threadIdx.x) * 4;
    if (i >= npad) return;
    ushort4 o;
    if (i + 4 <= n) {
        float4 v = *(const float4*)&src[i];
        o.x = f2bf(v.x); o.y = f2bf(v.y); o.z = f2bf(v.z); o.w = f2bf(v.w);
    } else {
        float vv[4];
#pragma unroll
        for (int j = 0; j < 4; ++j) vv[j] = (i + j < n) ? src[i + j] : 0.f;
        o.x = f2bf(vv[0]); o.y = f2bf(vv[1]); o.z = f2bf(vv[2]); o.w = f2bf(vv[3]);
    }
    *(ushort4*)&dst[i] = o;
}

__global__ void transpose_cast(const float* __restrict__ W, unsigned short* __restrict__ Wt)
{   // Wt[n][k] = bf16(W[k][n]); 256x256
    int n = blockIdx.x, k = threadIdx.x;
    Wt[n * 256 + k] = f2bf(W[k * 256 + n]);
}

__global__ void blend_k(const unsigned short* __restrict__ a, const unsigned short* __restrict__ b,
                        const float* __restrict__ attn, unsigned short* __restrict__ o, long n)
{
    long i = ((long)blockIdx.x * 256 + threadIdx.x) * 4;
    if (i >= n) return;
    float a0 = attn[0], a1 = attn[1];
    ushort4 ua = *(const ushort4*)&a[i];
    ushort4 ub = *(const ushort4*)&b[i];
    ushort4 uo;
    uo.x = f2bf(a0 * bf2f(ua.x) + a1 * bf2f(ub.x));
    uo.y = f2bf(a0 * bf2f(ua.y) + a1 * bf2f(ub.y));
    uo.z = f2bf(a0 * bf2f(ua.z) + a1 * bf2f(ub.z));
    uo.w = f2bf(a0 * bf2f(ua.w) + a1 * bf2f(ub.w));
    *(ushort4*)&o[i] = uo;
}

// ---------------- per-node attention logits ----------------
__launch_bounds__(256)
__global__ void node_al(const float* __restrict__ x, int N,
                        const float* __restrict__ a0, const float* __restrict__ a1,
                        const float* __restrict__ a2,
                        float* __restrict__ o0, float* __restrict__ o1, float* __restrict__ o2,
                        int nv)
{
    int wid  = (int)((blockIdx.x * 256 + threadIdx.x) >> 6);
    int lane = threadIdx.x & 63;
    if (wid >= N) return;
    float xv[4];
#pragma unroll
    for (int h = 0; h < 4; ++h) xv[h] = x[(size_t)wid * 256 + h * 64 + lane];
    for (int v = 0; v < nv; ++v) {
        const float* a = (v == 0) ? a0 : (v == 1 ? a1 : a2);
        float* o       = (v == 0) ? o0 : (v == 1 ? o1 : o2);
        float p0 = xv[0] * a[lane];
        float p1 = xv[1] * a[64 + lane];
        float p2 = xv[2] * a[128 + lane];
        float p3 = xv[3] * a[192 + lane];
#pragma unroll
        for (int off = 32; off > 0; off >>= 1) {
            p0 += __shfl_xor(p0, off);
            p1 += __shfl_xor(p1, off);
            p2 += __shfl_xor(p2, off);
            p3 += __shfl_xor(p3, off);
        }
        if (lane == 0) {
            o[(size_t)wid * 4 + 0] = p0;
            o[(size_t)wid * 4 + 1] = p1;
            o[(size_t)wid * 4 + 2] = p2;
            o[(size_t)wid * 4 + 3] = p3;
        }
    }
}

// ---------------- CSR build ----------------
__global__ void hist_k(const int* __restrict__ dst, int E, int* __restrict__ deg)
{
    int e = blockIdx.x * 256 + threadIdx.x;
    if (e < E) atomicAdd(&deg[dst[e]], 1);
}

__global__ void scan_bsum(const int* __restrict__ deg, int n, int* __restrict__ part)
{
    __shared__ int smem[SCAN_B];
    int i = blockIdx.x * SCAN_B + threadIdx.x;
    smem[threadIdx.x] = (i < n) ? deg[i] : 0;
    __syncthreads();
    for (int off = SCAN_B / 2; off > 0; off >>= 1) {
        if (threadIdx.x < off) smem[threadIdx.x] += smem[threadIdx.x + off];
        __syncthreads();
    }
    if (threadIdx.x == 0) part[blockIdx.x] = smem[0];
}

__global__ void scan_part(int* __restrict__ part, int nb)
{
    __shared__ int smem[1024];
    int t = threadIdx.x;
    int v = (t < nb) ? part[t] : 0;
    smem[t] = v;
    __syncthreads();
    for (int off = 1; off < 1024; off <<= 1) {
        int add = (t >= off) ? smem[t - off] : 0;
        __syncthreads();
        smem[t] += add;
        __syncthreads();
    }
    if (t < nb) part[t] = smem[t] - v;
}

__global__ void scan_final(const int* __restrict__ deg, int n, const int* __restrict__ part,
                           int* __restrict__ rowptr, int E)
{
    __shared__ int smem[SCAN_B];
    int t = threadIdx.x;
    int i = blockIdx.x * SCAN_B + t;
    int v = (i < n) ? deg[i] : 0;
    smem[t] = v;
    __syncthreads();
    for (int off = 1; off < SCAN_B; off <<= 1) {
        int add = (t >= off) ? smem[t - off] : 0;
        __syncthreads();
        smem[t] += add;
        __syncthreads();
    }
    if (i < n) rowptr[i] = part[blockIdx.x] + smem[t] - v;
    if (blockIdx.x == 0 && t == 0) rowptr[n] = E;
}

__global__ void fill_csr(const int* __restrict__ dst, int E, const int* __restrict__ rowptr,
                         int* __restrict__ cur, int* __restrict__ csr)
{
    int e = blockIdx.x * 256 + threadIdx.x;
    if (e >= E) return;
    int d = dst[e];
    int slot = atomicAdd(&cur[d], 1);
    csr[rowptr[d] + slot] = e;
}

// ======== fused per-dst GAT: softmax over incoming edges + gather, no atomics ========
// one wave per dst node. Phase 1 (edge-parallel): lane l owns edge beg+l; computes
// al = lrelu(als[src]+ald[dst]), wave-max per head, w=exp(al-m), per-lane denom partials;
// stash (src, w[4]) in this wave's LDS slice. Phase 2 (dim-parallel): broadcast-gather
// sum w_e * x[src_e]; divide by reduced denom; relu; bf16 store.
__launch_bounds__(256)
__global__ void gat_fused(const float* __restrict__ xsrc,
                          const float* __restrict__ als,   // [Nsrc][4]
                          const float* __restrict__ ald,   // [Ndst][4]
                          const int* __restrict__ rowptr, const int* __restrict__ csr,
                          const int* __restrict__ src, int N,
                          unsigned short* __restrict__ outb)
{
    __shared__ float lw[4][64 * 4];
    __shared__ int   ls[4][64];
    const int wv   = threadIdx.x >> 6;
    const int w    = (int)((blockIdx.x * 256 + threadIdx.x) >> 6);
    const int lane = threadIdx.x & 63;
    if (w >= N) return;
    const int beg = rowptr[w], end = rowptr[w + 1];
    const int deg = end - beg;
    const int h = lane >> 4;
    const float4 d4 = *(const float4*)&ald[(size_t)w * 4];

    float4 acc = make_float4(0.f, 0.f, 0.f, 0.f);
    float dn0 = 0.f, dn1 = 0.f, dn2 = 0.f, dn3 = 0.f;

    if (deg <= 64) {
        // ---- fast path: single chunk, everything stays in registers ----
        float al0 = NEG_BIG, al1 = NEG_BIG, al2 = NEG_BIG, al3 = NEG_BIG;
        int es = 0;
        if (lane < deg) {
            int e = csr[beg + lane];
            es = src[e];
            float4 a = *(const float4*)&als[(size_t)es * 4];
            al0 = lrelu(a.x + d4.x); al1 = lrelu(a.y + d4.y);
            al2 = lrelu(a.z + d4.z); al3 = lrelu(a.w + d4.w);
        }
        float m0 = al0, m1 = al1, m2 = al2, m3 = al3;
#pragma unroll
        for (int off = 32; off > 0; off >>= 1) {
            m0 = fmaxf(m0, __shfl_xor(m0, off));
            m1 = fmaxf(m1, __shfl_xor(m1, off));
            m2 = fmaxf(m2, __shfl_xor(m2, off));
            m3 = fmaxf(m3, __shfl_xor(m3, off));
        }
        float w0 = 0.f, w1 = 0.f, w2 = 0.f, w3 = 0.f;
        if (lane < deg) {
            w0 = expf(al0 - m0); w1 = expf(al1 - m1);
            w2 = expf(al2 - m2); w3 = expf(al3 - m3);
            ls[wv][lane] = es;
            lw[wv][lane * 4 + 0] = w0; lw[wv][lane * 4 + 1] = w1;
            lw[wv][lane * 4 + 2] = w2; lw[wv][lane * 4 + 3] = w3;
        }
        dn0 = w0; dn1 = w1; dn2 = w2; dn3 = w3;
        for (int i = 0; i < deg; ++i) {
            int s = ls[wv][i];
            float wx = lw[wv][i * 4 + h];
            float4 x = *(const float4*)&xsrc[(size_t)s * 256 + (lane << 2)];
            acc.x += wx * x.x; acc.y += wx * x.y;
            acc.z += wx * x.z; acc.w += wx * x.w;
        }
    } else {
        // ---- general path (rare): pass 1 = global max, pass 2 = exp + gather ----
        float m0 = NEG_BIG, m1 = NEG_BIG, m2 = NEG_BIG, m3 = NEG_BIG;
        for (int c = beg; c < end; c += 64) {
            if (c + lane < end) {
                int e = csr[c + lane];
                int s = src[e];
                float4 a = *(const float4*)&als[(size_t)s * 4];
                m0 = fmaxf(m0, lrelu(a.x + d4.x)); m1 = fmaxf(m1, lrelu(a.y + d4.y));
                m2 = fmaxf(m2, lrelu(a.z + d4.z)); m3 = fmaxf(m3, lrelu(a.w + d4.w));
            }
        }
#pragma unroll
        for (int off = 32; off > 0; off >>= 1) {
            m0 = fmaxf(m0, __shfl_xor(m0, off));
            m1 = fmaxf(m1, __shfl_xor(m1, off));
            m2 = fmaxf(m2, __shfl_xor(m2, off));
            m3 = fmaxf(m3, __shfl_xor(m3, off));
        }
        for (int c = beg; c < end; c += 64) {
            int cnt = min(64, end - c);
            if (lane < cnt) {
                int e = csr[c + lane];
                int es = src[e];
                float4 a = *(const float4*)&als[(size_t)es * 4];
                float w0 = expf(lrelu(a.x + d4.x) - m0);
                float w1 = expf(lrelu(a.y + d4.y) - m1);
                float w2 = expf(lrelu(a.z + d4.z) - m2);
                float w3 = expf(lrelu(a.w + d4.w) - m3);
                ls[wv][lane] = es;
                lw[wv][lane * 4 + 0] = w0; lw[wv][lane * 4 + 1] = w1;
                lw[wv][lane * 4 + 2] = w2; lw[wv][lane * 4 + 3] = w3;
                dn0 += w0; dn1 += w1; dn2 += w2; dn3 += w3;
            }
            for (int i = 0; i < cnt; ++i) {
                int s = ls[wv][i];
                float wx = lw[wv][i * 4 + h];
                float4 x = *(const float4*)&xsrc[(size_t)s * 256 + (lane << 2)];
                acc.x += wx * x.x; acc.y += wx * x.y;
                acc.z += wx * x.z; acc.w += wx * x.w;
            }
        }
    }

    // reduce denominators across lanes, select this lane's head
#pragma unroll
    for (int off = 32; off > 0; off >>= 1) {
        dn0 += __shfl_xor(dn0, off);
        dn1 += __shfl_xor(dn1, off);
        dn2 += __shfl_xor(dn2, off);
        dn3 += __shfl_xor(dn3, off);
    }
    float dh = (h == 0) ? dn0 : (h == 1) ? dn1 : (h == 2) ? dn2 : dn3;
    float inv = 1.f / (dh + 1e-16f);
    ushort4 uo;
    uo.x = f2bf(fmaxf(acc.x * inv, 0.f));
    uo.y = f2bf(fmaxf(acc.y * inv, 0.f));
    uo.z = f2bf(fmaxf(acc.z * inv, 0.f));
    uo.w = f2bf(fmaxf(acc.w * inv, 0.f));
    *(ushort4*)&outb[(size_t)w * 256 + (lane << 2)] = uo;
}

__global__ void attn_k(const float* __restrict__ score, float* __restrict__ attn, float invN)
{
    if (threadIdx.x == 0 && blockIdx.x == 0) {
        float s0 = score[0] * invN, s1 = score[1] * invN;
        float m  = fmaxf(s0, s1);
        float e0 = expf(s0 - m), e1 = expf(s1 - m);
        float dsum = e0 + e1;
        attn[0] = e0 / dsum;
        attn[1] = e1 / dsum;
    }
}

extern "C" void kernel_launch(void* const* d_in, const int* in_sizes, int n_in,
                              void* d_out, int out_size, void* d_ws, size_t ws_size,
                              hipStream_t stream)
{
    const float* x_job    = (const float*)d_in[0];
    const float* x_skill  = (const float*)d_in[1];
    const float* W_job    = (const float*)d_in[2];
    const float* b_job    = (const float*)d_in[3];
    const float* W_skill  = (const float*)d_in[4];
    const float* b_skill  = (const float*)d_in[5];
    const float* a_src_sj = (const float*)d_in[6];
    const float* a_dst_sj = (const float*)d_in[7];
    const float* a_src_jj = (const float*)d_in[8];
    const float* a_dst_jj = (const float*)d_in[9];
    // d_in[10], d_in[11]: a_src_js / a_dst_js — js edge-type output unused by the head; skipped.
    const float* q_vec = (const float*)d_in[12];
    const float* Wk    = (const float*)d_in[13];
    const float* bk    = (const float*)d_in[14];
    const float* W1    = (const float*)d_in[15];
    const float* b1    = (const float*)d_in[16];
    const float* W2    = (const float*)d_in[17];
    const float* b2    = (const float*)d_in[18];
    const int* ei_sj_src = (const int*)d_in[19];
    const int* ei_sj_dst = (const int*)d_in[20];
    const int* ei_jj_src = (const int*)d_in[21];
    const int* ei_jj_dst = (const int*)d_in[22];

    const int NJ   = in_sizes[0] / 256;
    const int NS   = in_sizes[1] / 256;
    const int E_sj = in_sizes[19];
    const int E_jj = in_sizes[21];
    const int gmJ  = (NJ + 127) / 128, gmS = (NS + 127) / 128;
    const long MpadJ = (long)gmJ * 128, MpadS = (long)gmS * 128;

    char* ws   = (char*)d_ws;
    size_t off = 0;
    auto alloc = [&](size_t bytes) { void* p = ws + off; off += (bytes + 255) & ~(size_t)255; return p; };
    float* h_job   = (float*)alloc(MpadJ * 256 * 4);
    float* h_skill = (float*)alloc(MpadS * 256 * 4);
    unsigned short* x_job_bf   = (unsigned short*)alloc(MpadJ * 256 * 2);
    unsigned short* x_skill_bf = (unsigned short*)alloc(MpadS * 256 * 2);
    unsigned short* Wjob_t  = (unsigned short*)alloc(256 * 256 * 2);
    unsigned short* Wskl_t  = (unsigned short*)alloc(256 * 256 * 2);
    unsigned short* Wk_t    = (unsigned short*)alloc(256 * 256 * 2);
    unsigned short* W1_t    = (unsigned short*)alloc(256 * 256 * 2);
    unsigned short* out_sj_bf = (unsigned short*)alloc(MpadJ * 256 * 2);
    unsigned short* out_jj_bf = (unsigned short*)alloc(MpadJ * 256 * 2);
    unsigned short* ablend = x_job_bf;   // alias: x_job_bf dead after proj GEMM
    float* ald_sj  = (float*)alloc((size_t)NJ * 4 * 4);
    float* als_jj  = (float*)alloc((size_t)NJ * 4 * 4);
    float* ald_jj  = (float*)alloc((size_t)NJ * 4 * 4);
    float* als_sj  = (float*)alloc((size_t)NS * 4 * 4);
    float* score  = (float*)alloc(64 * 4);   // [0..1] raw scores, [2..3] attn
    float* attn   = score + 2;
    int* deg_sj = (int*)alloc((size_t)NJ * 4);
    int* deg_jj = (int*)alloc((size_t)NJ * 4);
    int* rp_sj  = (int*)alloc(((size_t)NJ + 1) * 4);
    int* rp_jj  = (int*)alloc(((size_t)NJ + 1) * 4);
    int* part_a = (int*)alloc(1024 * 4);
    int* part_b = (int*)alloc(1024 * 4);
    int* cur_sj = (int*)alloc((size_t)NJ * 4);
    int* cur_jj = (int*)alloc((size_t)NJ * 4);
    int* csr_sj = (int*)alloc((size_t)E_sj * 4);
    int* csr_jj = (int*)alloc((size_t)E_jj * 4);
    (void)ws_size; (void)n_in;

    hipMemsetAsync(score,  0, 2 * 4, stream);
    hipMemsetAsync(deg_sj, 0, (size_t)NJ * 4, stream);
    hipMemsetAsync(deg_jj, 0, (size_t)NJ * 4, stream);
    hipMemsetAsync(cur_sj, 0, (size_t)NJ * 4, stream);
    hipMemsetAsync(cur_jj, 0, (size_t)NJ * 4, stream);

    dim3 blk(256);
    int nbJ = (NJ + SCAN_B - 1) / SCAN_B;

    // ---- casts & weight transposes ----
    long nJ = (long)NJ * 256, nJp = MpadJ * 256;
    long nS = (long)NS * 256, nSp = MpadS * 256;
    cast_pad<<<dim3((int)((nJp / 4 + 255) / 256)), blk, 0, stream>>>(x_job, x_job_bf, nJ, nJp);
    cast_pad<<<dim3((int)((nSp / 4 + 255) / 256)), blk, 0, stream>>>(x_skill, x_skill_bf, nS, nSp);
    transpose_cast<<<dim3(256), blk, 0, stream>>>(W_job, Wjob_t);
    transpose_cast<<<dim3(256), blk, 0, stream>>>(W_skill, Wskl_t);
    transpose_cast<<<dim3(256), blk, 0, stream>>>(Wk, Wk_t);
    transpose_cast<<<dim3(256), blk, 0, stream>>>(W1, W1_t);

    // ---- CSR build ----
    hist_k<<<dim3((E_sj + 255) / 256), blk, 0, stream>>>(ei_sj_dst, E_sj, deg_sj);
    hist_k<<<dim3((E_jj + 255) / 256), blk, 0, stream>>>(ei_jj_dst, E_jj, deg_jj);
    scan_bsum<<<dim3(nbJ), dim3(SCAN_B), 0, stream>>>(deg_sj, NJ, part_a);
    scan_bsum<<<dim3(nbJ), dim3(SCAN_B), 0, stream>>>(deg_jj, NJ, part_b);
    scan_part<<<dim3(1), dim3(1024), 0, stream>>>(part_a, nbJ);
    scan_part<<<dim3(1), dim3(1024), 0, stream>>>(part_b, nbJ);
    scan_final<<<dim3(nbJ), dim3(SCAN_B), 0, stream>>>(deg_sj, NJ, part_a, rp_sj, E_sj);
    scan_final<<<dim3(nbJ), dim3(SCAN_B), 0, stream>>>(deg_jj, NJ, part_b, rp_jj, E_jj);
    fill_csr<<<dim3((E_sj + 255) / 256), blk, 0, stream>>>(ei_sj_dst, E_sj, rp_sj, cur_sj, csr_sj);
    fill_csr<<<dim3((E_jj + 255) / 256), blk, 0, stream>>>(ei_jj_dst, E_jj, rp_jj, cur_jj, csr_jj);

    // ---- input projections (MFMA) ----
    gemm_mfma<0><<<dim3(gmJ), dim3(512), 0, stream>>>(x_job_bf, Wjob_t, b_job,
                                                      nullptr, nullptr, h_job, nullptr, NJ);
    gemm_mfma<0><<<dim3(gmS), dim3(512), 0, stream>>>(x_skill_bf, Wskl_t, b_skill,
                                                      nullptr, nullptr, h_skill, nullptr, NS);

    // ---- node-level attention logits ----
    node_al<<<dim3((NJ * 64 + 255) / 256), blk, 0, stream>>>(
        h_job, NJ, a_dst_sj, a_src_jj, a_dst_jj, ald_sj, als_jj, ald_jj, 3);
    node_al<<<dim3((NS * 64 + 255) / 256), blk, 0, stream>>>(
        h_skill, NS, a_src_sj, nullptr, nullptr, als_sj, nullptr, nullptr, 1);

    // ---- fused per-dst GAT (softmax + gather, no atomics) ----
    gat_fused<<<dim3((NJ + 3) / 4), blk, 0, stream>>>(
        h_skill, als_sj, ald_sj, rp_sj, csr_sj, ei_sj_src, NJ, out_sj_bf);
    gat_fused<<<dim3((NJ + 3) / 4), blk, 0, stream>>>(
        h_job, als_jj, ald_jj, rp_jj, csr_jj, ei_jj_src, NJ, out_jj_bf);

    // ---- semantic attention scores (MFMA, fused tanh + q-dot + sum) ----
    gemm_mfma<1><<<dim3(gmJ), dim3(512), 0, stream>>>(out_sj_bf, Wk_t, bk,
                                                      q_vec, nullptr, nullptr, &score[0], NJ);
    gemm_mfma<1><<<dim3(gmJ), dim3(512), 0, stream>>>(out_jj_bf, Wk_t, bk,
                                                      q_vec, nullptr, nullptr, &score[1], NJ);
    attn_k<<<1, 64, 0, stream>>>(score, attn, 1.0f / (float)NJ);

    // ---- blend (bf16) then head (MFMA, fused relu + W2-dot + b2) ----
    blend_k<<<dim3((int)((nJ / 4 + 255) / 256)), blk, 0, stream>>>(
        out_sj_bf, out_jj_bf, attn, ablend, nJ);
    gemm_mfma<2><<<dim3(gmJ), dim3(512), 0, stream>>>(ablend, W1_t, b1,
                                                      W2, b2, (float*)d_out, nullptr, NJ);
}

// Round 7
// 534.193 us; speedup vs baseline: 8.6778x; 1.2290x over previous
//
#include <hip/hip_runtime.h>
#include <hip/hip_bf16.h>
#include <math.h>

#define SCAN_B 256
#define NEG_BIG (-3.0e38f)

typedef __attribute__((ext_vector_type(8))) short bf16x8;   // 8 bf16 = 4 VGPR
typedef __attribute__((ext_vector_type(4))) float f32x4;

__device__ __forceinline__ unsigned short f2bf(float f) {
    __hip_bfloat16 h = __float2bfloat16(f);   // RNE
    return *(unsigned short*)&h;
}
__device__ __forceinline__ float bf2f(unsigned short u) {
    unsigned v = ((unsigned)u) << 16;
    return __uint_as_float(v);
}
__device__ __forceinline__ float lrelu(float x) { return (x >= 0.f) ? x : 0.2f * x; }

// blend two packed bf16 pairs: r = bf16(c0*a + c1*b) lane-wise
__device__ __forceinline__ unsigned blend2(unsigned a, unsigned b, float c0, float c1) {
    float alo = bf2f((unsigned short)(a & 0xffff)), ahi = bf2f((unsigned short)(a >> 16));
    float blo = bf2f((unsigned short)(b & 0xffff)), bhi = bf2f((unsigned short)(b >> 16));
    unsigned short rlo = f2bf(c0 * alo + c1 * blo);
    unsigned short rhi = f2bf(c0 * ahi + c1 * bhi);
    return (unsigned)rlo | ((unsigned)rhi << 16);
}

// =============== MFMA GEMM: A[Mpad,256]bf16 @ B^T[256n,256k]bf16 ===============
// 128x256 tile, BK=64, 512 thr = 8 waves (2 row x 4 col of 64x64), 16x16x32 bf16.
// MODE 0: outh[M,256] = bf16(A@B + bias); ALSO per-head logits: for v<NV,
//         lo_v[row*4+wc] = sum_{col in head wc} h*av_v   (head = col/64 = wc)
// MODE 1: A selected by blockIdx.y (Abf / A2bf); atomicAdd(scoreSlot[y],
//         sum_rows q . tanh(A@B + bias))
// MODE 2: A' = bf16(attn0*A + attn1*A2) blended at stage time;
//         outf[row] = sum_j relu((A'@B)[row,j]+bias[j]) * vq[j] + b2p[0]
template<int MODE, int NV>
__launch_bounds__(512)
__global__ void gemm_mfma(const unsigned short* __restrict__ Abf,
                          const unsigned short* __restrict__ A2bf,
                          const unsigned short* __restrict__ Bt,
                          const float* __restrict__ bias,
                          const float* __restrict__ vq,
                          const float* __restrict__ b2p,
                          const float* __restrict__ attn2,
                          unsigned short* __restrict__ outh,
                          float* __restrict__ outf,
                          float* __restrict__ scoreSlot,
                          const float* __restrict__ av0,
                          const float* __restrict__ av1,
                          const float* __restrict__ av2,
                          float* __restrict__ lo0,
                          float* __restrict__ lo1,
                          float* __restrict__ lo2,
                          int M)
{
    __shared__ __align__(16) char sm[49152];   // A:[0,16K)=[128][64]bf16; B^T:[16K,48K)=[256][64]bf16
    __shared__ float red8[8];
    const int t    = threadIdx.x;
    const int lane = t & 63, wid = t >> 6;
    const int wr = wid >> 2, wc = wid & 3;
    const long row0 = (long)blockIdx.x * 128;
    const char* Ab = (const char*)((MODE == 1 && blockIdx.y == 1) ? A2bf : Abf);
    const char* A2 = (const char*)A2bf;
    const char* Bb = (const char*)Bt;

    float blend0 = 0.f, blend1 = 0.f;
    if (MODE == 2) { blend0 = attn2[0]; blend1 = attn2[1]; }

    f32x4 acc[4][4];
#pragma unroll
    for (int m = 0; m < 4; ++m)
#pragma unroll
        for (int n = 0; n < 4; ++n) acc[m][n] = (f32x4){0.f, 0.f, 0.f, 0.f};

    for (int k0 = 0; k0 < 256; k0 += 64) {
#pragma unroll
        for (int rep = 0; rep < 2; ++rep) {
            int idx = rep * 512 + t;
            int row = idx >> 3, colb = (idx & 7) << 4;
            uint4 v = *(const uint4*)(Ab + (row0 + row) * 512 + k0 * 2 + colb);
            if (MODE == 2) {
                uint4 v2 = *(const uint4*)(A2 + (row0 + row) * 512 + k0 * 2 + colb);
                v.x = blend2(v.x, v2.x, blend0, blend1);
                v.y = blend2(v.y, v2.y, blend0, blend1);
                v.z = blend2(v.z, v2.z, blend0, blend1);
                v.w = blend2(v.w, v2.w, blend0, blend1);
            }
            *(uint4*)&sm[row * 128 + (colb ^ ((row & 7) << 4))] = v;
        }
#pragma unroll
        for (int rep = 0; rep < 4; ++rep) {
            int idx = rep * 512 + t;
            int n = idx >> 3, colb = (idx & 7) << 4;
            uint4 v = *(const uint4*)(Bb + n * 512 + k0 * 2 + colb);
            *(uint4*)&sm[16384 + n * 128 + (colb ^ ((n & 7) << 4))] = v;
        }
        __syncthreads();
#pragma unroll
        for (int kki = 0; kki < 2; ++kki) {
            const int kb = kki * 64 + ((lane >> 4) << 4);
            bf16x8 a[4], b[4];
#pragma unroll
            for (int m = 0; m < 4; ++m) {
                int row = wr * 64 + m * 16 + (lane & 15);
                a[m] = *(const bf16x8*)&sm[row * 128 + (kb ^ ((row & 7) << 4))];
            }
#pragma unroll
            for (int n = 0; n < 4; ++n) {
                int nr = wc * 64 + n * 16 + (lane & 15);
                b[n] = *(const bf16x8*)&sm[16384 + nr * 128 + (kb ^ ((nr & 7) << 4))];
            }
#pragma unroll
            for (int m = 0; m < 4; ++m)
#pragma unroll
                for (int n = 0; n < 4; ++n)
                    acc[m][n] = __builtin_amdgcn_mfma_f32_16x16x32_bf16(a[m], b[n], acc[m][n], 0, 0, 0);
        }
        __syncthreads();
    }

    const int colbase = wc * 64 + (lane & 15);
    const int rbase   = wr * 64 + ((lane >> 4) << 2);
    float bv[4];
#pragma unroll
    for (int n = 0; n < 4; ++n) bv[n] = bias[colbase + n * 16];

    if (MODE == 0) {
        // per-lane a-vector values at this lane's 4 cols (head == wc)
        float areg[(NV > 0) ? NV : 1][4];
#pragma unroll
        for (int v = 0; v < NV; ++v) {
            const float* av = (v == 0) ? av0 : (v == 1) ? av1 : av2;
#pragma unroll
            for (int n = 0; n < 4; ++n) areg[v][n] = av[colbase + n * 16];
        }
#pragma unroll
        for (int m = 0; m < 4; ++m) {
#pragma unroll
            for (int j = 0; j < 4; ++j) {
                long row = row0 + rbase + m * 16 + j;
                float hv[4];
#pragma unroll
                for (int n = 0; n < 4; ++n) hv[n] = acc[m][n][j] + bv[n];
                if (row < M) {
#pragma unroll
                    for (int n = 0; n < 4; ++n)
                        outh[row * 256 + colbase + n * 16] = f2bf(hv[n]);
                }
#pragma unroll
                for (int v = 0; v < NV; ++v) {
                    float p = hv[0] * areg[v][0] + hv[1] * areg[v][1]
                            + hv[2] * areg[v][2] + hv[3] * areg[v][3];
                    p += __shfl_xor(p, 1); p += __shfl_xor(p, 2);
                    p += __shfl_xor(p, 4); p += __shfl_xor(p, 8);
                    if ((lane & 15) == 0 && row < M) {
                        float* lo = (v == 0) ? lo0 : (v == 1) ? lo1 : lo2;
                        lo[row * 4 + wc] = p;
                    }
                }
            }
        }
    } else if (MODE == 1) {
        float p = 0.f;
        float qv[4];
#pragma unroll
        for (int n = 0; n < 4; ++n) qv[n] = vq[colbase + n * 16];
#pragma unroll
        for (int n = 0; n < 4; ++n) {
#pragma unroll
            for (int m = 0; m < 4; ++m) {
                long row = row0 + rbase + m * 16;
#pragma unroll
                for (int j = 0; j < 4; ++j)
                    if (row + j < M) p += qv[n] * tanhf(acc[m][n][j] + bv[n]);
            }
        }
#pragma unroll
        for (int off = 32; off > 0; off >>= 1) p += __shfl_xor(p, off);
        if (lane == 0) red8[wid] = p;
        __syncthreads();
        if (t == 0) {
            float s = 0.f;
#pragma unroll
            for (int i = 0; i < 8; ++i) s += red8[i];
            atomicAdd(&scoreSlot[blockIdx.y], s);
        }
    } else {
        float* redC = (float*)sm;   // reuse tile buffer (free after final barrier)
        float b2v = b2p[0];
        float wv[4];
#pragma unroll
        for (int n = 0; n < 4; ++n) wv[n] = vq[colbase + n * 16];
#pragma unroll
        for (int m = 0; m < 4; ++m) {
#pragma unroll
            for (int j = 0; j < 4; ++j) {
                float s = 0.f;
#pragma unroll
                for (int n = 0; n < 4; ++n)
                    s += fmaxf(acc[m][n][j] + bv[n], 0.f) * wv[n];
                s += __shfl_xor(s, 1); s += __shfl_xor(s, 2);
                s += __shfl_xor(s, 4); s += __shfl_xor(s, 8);
                if ((lane & 15) == 0) {
                    int lrow = wr * 64 + m * 16 + ((lane >> 4) << 2) + j;
                    redC[lrow * 4 + wc] = s;
                }
            }
        }
        __syncthreads();
        if (t < 128) {
            long row = row0 + t;
            if (row < M)
                outf[row] = redC[t * 4 + 0] + redC[t * 4 + 1]
                          + redC[t * 4 + 2] + redC[t * 4 + 3] + b2v;
        }
    }
}

// ---------------- casts / transposes ----------------
__global__ void cast_pad(const float* __restrict__ src, unsigned short* __restrict__ dst,
                         long n, long npad)
{
    long i = ((long)blockIdx.x * 256 + threadIdx.x) * 4;
    if (i >= npad) return;
    ushort4 o;
    if (i + 4 <= n) {
        float4 v = *(const float4*)&src[i];
        o.x = f2bf(v.x); o.y = f2bf(v.y); o.z = f2bf(v.z); o.w = f2bf(v.w);
    } else {
        float vv[4];
#pragma unroll
        for (int j = 0; j < 4; ++j) vv[j] = (i + j < n) ? src[i + j] : 0.f;
        o.x = f2bf(vv[0]); o.y = f2bf(vv[1]); o.z = f2bf(vv[2]); o.w = f2bf(vv[3]);
    }
    *(ushort4*)&dst[i] = o;
}

__global__ void transpose_cast(const float* __restrict__ W, unsigned short* __restrict__ Wt)
{   // Wt[n][k] = bf16(W[k][n]); 256x256
    int n = blockIdx.x, k = threadIdx.x;
    Wt[n * 256 + k] = f2bf(W[k * 256 + n]);
}

// ---------------- CSR build ----------------
__global__ void hist_k(const int* __restrict__ dst, int E, int* __restrict__ deg)
{
    int e = blockIdx.x * 256 + threadIdx.x;
    if (e < E) atomicAdd(&deg[dst[e]], 1);
}

__global__ void scan_bsum(const int* __restrict__ deg, int n, int* __restrict__ part)
{
    __shared__ int smem[SCAN_B];
    int i = blockIdx.x * SCAN_B + threadIdx.x;
    smem[threadIdx.x] = (i < n) ? deg[i] : 0;
    __syncthreads();
    for (int off = SCAN_B / 2; off > 0; off >>= 1) {
        if (threadIdx.x < off) smem[threadIdx.x] += smem[threadIdx.x + off];
        __syncthreads();
    }
    if (threadIdx.x == 0) part[blockIdx.x] = smem[0];
}

__global__ void scan_part(int* __restrict__ part, int nb)
{
    __shared__ int smem[1024];
    int t = threadIdx.x;
    int v = (t < nb) ? part[t] : 0;
    smem[t] = v;
    __syncthreads();
    for (int off = 1; off < 1024; off <<= 1) {
        int add = (t >= off) ? smem[t - off] : 0;
        __syncthreads();
        smem[t] += add;
        __syncthreads();
    }
    if (t < nb) part[t] = smem[t] - v;
}

__global__ void scan_final(const int* __restrict__ deg, int n, const int* __restrict__ part,
                           int* __restrict__ rowptr, int E)
{
    __shared__ int smem[SCAN_B];
    int t = threadIdx.x;
    int i = blockIdx.x * SCAN_B + t;
    int v = (i < n) ? deg[i] : 0;
    smem[t] = v;
    __syncthreads();
    for (int off = 1; off < SCAN_B; off <<= 1) {
        int add = (t >= off) ? smem[t - off] : 0;
        __syncthreads();
        smem[t] += add;
        __syncthreads();
    }
    if (i < n) rowptr[i] = part[blockIdx.x] + smem[t] - v;
    if (blockIdx.x == 0 && t == 0) rowptr[n] = E;
}

__global__ void fill_csr(const int* __restrict__ dst, int E, const int* __restrict__ rowptr,
                         int* __restrict__ cur, int* __restrict__ csr)
{
    int e = blockIdx.x * 256 + threadIdx.x;
    if (e >= E) return;
    int d = dst[e];
    int slot = atomicAdd(&cur[d], 1);
    csr[rowptr[d] + slot] = e;
}

// ======== fused per-dst GAT (merged over gridDim.y = 2 edge types) ========
// one wave per dst node; bf16 x tables; softmax fully in-wave; no atomics.
__launch_bounds__(256)
__global__ void gat_fused(const unsigned short* __restrict__ xs0,
                          const unsigned short* __restrict__ xs1,
                          const float* __restrict__ als0, const float* __restrict__ als1,
                          const float* __restrict__ ald0, const float* __restrict__ ald1,
                          const int* __restrict__ rp0, const int* __restrict__ rp1,
                          const int* __restrict__ csr0, const int* __restrict__ csr1,
                          const int* __restrict__ src0, const int* __restrict__ src1,
                          int N,
                          unsigned short* __restrict__ out0,
                          unsigned short* __restrict__ out1)
{
    const int et = blockIdx.y;
    const unsigned short* xsrc = et ? xs1 : xs0;
    const float* als = et ? als1 : als0;
    const float* ald = et ? ald1 : ald0;
    const int* rowptr = et ? rp1 : rp0;
    const int* csr    = et ? csr1 : csr0;
    const int* src    = et ? src1 : src0;
    unsigned short* outb = et ? out1 : out0;

    __shared__ float lw[4][64 * 4];
    __shared__ int   ls[4][64];
    const int wv   = threadIdx.x >> 6;
    const int w    = (int)((blockIdx.x * 256 + threadIdx.x) >> 6);
    const int lane = threadIdx.x & 63;
    if (w >= N) return;
    const int beg = rowptr[w], end = rowptr[w + 1];
    const int deg = end - beg;
    const int h = lane >> 4;
    const float4 d4 = *(const float4*)&ald[(size_t)w * 4];

    float4 acc = make_float4(0.f, 0.f, 0.f, 0.f);
    float dn0 = 0.f, dn1 = 0.f, dn2 = 0.f, dn3 = 0.f;

    if (deg <= 64) {
        float al0 = NEG_BIG, al1 = NEG_BIG, al2 = NEG_BIG, al3 = NEG_BIG;
        int es = 0;
        if (lane < deg) {
            int e = csr[beg + lane];
            es = src[e];
            float4 a = *(const float4*)&als[(size_t)es * 4];
            al0 = lrelu(a.x + d4.x); al1 = lrelu(a.y + d4.y);
            al2 = lrelu(a.z + d4.z); al3 = lrelu(a.w + d4.w);
        }
        float m0 = al0, m1 = al1, m2 = al2, m3 = al3;
#pragma unroll
        for (int off = 32; off > 0; off >>= 1) {
            m0 = fmaxf(m0, __shfl_xor(m0, off));
            m1 = fmaxf(m1, __shfl_xor(m1, off));
            m2 = fmaxf(m2, __shfl_xor(m2, off));
            m3 = fmaxf(m3, __shfl_xor(m3, off));
        }
        float w0 = 0.f, w1 = 0.f, w2 = 0.f, w3 = 0.f;
        if (lane < deg) {
            w0 = expf(al0 - m0); w1 = expf(al1 - m1);
            w2 = expf(al2 - m2); w3 = expf(al3 - m3);
            ls[wv][lane] = es;
            lw[wv][lane * 4 + 0] = w0; lw[wv][lane * 4 + 1] = w1;
            lw[wv][lane * 4 + 2] = w2; lw[wv][lane * 4 + 3] = w3;
        }
        dn0 = w0; dn1 = w1; dn2 = w2; dn3 = w3;
        for (int i = 0; i < deg; ++i) {
            int s = ls[wv][i];
            float wx = lw[wv][i * 4 + h];
            ushort4 xu = *(const ushort4*)&xsrc[(size_t)s * 256 + (lane << 2)];
            acc.x += wx * bf2f(xu.x); acc.y += wx * bf2f(xu.y);
            acc.z += wx * bf2f(xu.z); acc.w += wx * bf2f(xu.w);
        }
    } else {
        // general path (rare): pass 1 = global max, pass 2 = exp + gather
        float m0 = NEG_BIG, m1 = NEG_BIG, m2 = NEG_BIG, m3 = NEG_BIG;
        for (int c = beg; c < end; c += 64) {
            if (c + lane < end) {
                int e = csr[c + lane];
                int s = src[e];
                float4 a = *(const float4*)&als[(size_t)s * 4];
                m0 = fmaxf(m0, lrelu(a.x + d4.x)); m1 = fmaxf(m1, lrelu(a.y + d4.y));
                m2 = fmaxf(m2, lrelu(a.z + d4.z)); m3 = fmaxf(m3, lrelu(a.w + d4.w));
            }
        }
#pragma unroll
        for (int off = 32; off > 0; off >>= 1) {
            m0 = fmaxf(m0, __shfl_xor(m0, off));
            m1 = fmaxf(m1, __shfl_xor(m1, off));
            m2 = fmaxf(m2, __shfl_xor(m2, off));
            m3 = fmaxf(m3, __shfl_xor(m3, off));
        }
        for (int c = beg; c < end; c += 64) {
            int cnt = min(64, end - c);
            if (lane < cnt) {
                int e = csr[c + lane];
                int es = src[e];
                float4 a = *(const float4*)&als[(size_t)es * 4];
                float w0 = expf(lrelu(a.x + d4.x) - m0);
                float w1 = expf(lrelu(a.y + d4.y) - m1);
                float w2 = expf(lrelu(a.z + d4.z) - m2);
                float w3 = expf(lrelu(a.w + d4.w) - m3);
                ls[wv][lane] = es;
                lw[wv][lane * 4 + 0] = w0; lw[wv][lane * 4 + 1] = w1;
                lw[wv][lane * 4 + 2] = w2; lw[wv][lane * 4 + 3] = w3;
                dn0 += w0; dn1 += w1; dn2 += w2; dn3 += w3;
            }
            for (int i = 0; i < cnt; ++i) {
                int s = ls[wv][i];
                float wx = lw[wv][i * 4 + h];
                ushort4 xu = *(const ushort4*)&xsrc[(size_t)s * 256 + (lane << 2)];
                acc.x += wx * bf2f(xu.x); acc.y += wx * bf2f(xu.y);
                acc.z += wx * bf2f(xu.z); acc.w += wx * bf2f(xu.w);
            }
        }
    }

#pragma unroll
    for (int off = 32; off > 0; off >>= 1) {
        dn0 += __shfl_xor(dn0, off);
        dn1 += __shfl_xor(dn1, off);
        dn2 += __shfl_xor(dn2, off);
        dn3 += __shfl_xor(dn3, off);
    }
    float dh = (h == 0) ? dn0 : (h == 1) ? dn1 : (h == 2) ? dn2 : dn3;
    float inv = 1.f / (dh + 1e-16f);
    ushort4 uo;
    uo.x = f2bf(fmaxf(acc.x * inv, 0.f));
    uo.y = f2bf(fmaxf(acc.y * inv, 0.f));
    uo.z = f2bf(fmaxf(acc.z * inv, 0.f));
    uo.w = f2bf(fmaxf(acc.w * inv, 0.f));
    *(ushort4*)&outb[(size_t)w * 256 + (lane << 2)] = uo;
}

__global__ void attn_k(const float* __restrict__ score, float* __restrict__ attn, float invN)
{
    if (threadIdx.x == 0 && blockIdx.x == 0) {
        float s0 = score[0] * invN, s1 = score[1] * invN;
        float m  = fmaxf(s0, s1);
        float e0 = expf(s0 - m), e1 = expf(s1 - m);
        float dsum = e0 + e1;
        attn[0] = e0 / dsum;
        attn[1] = e1 / dsum;
    }
}

extern "C" void kernel_launch(void* const* d_in, const int* in_sizes, int n_in,
                              void* d_out, int out_size, void* d_ws, size_t ws_size,
                              hipStream_t stream)
{
    const float* x_job    = (const float*)d_in[0];
    const float* x_skill  = (const float*)d_in[1];
    const float* W_job    = (const float*)d_in[2];
    const float* b_job    = (const float*)d_in[3];
    const float* W_skill  = (const float*)d_in[4];
    const float* b_skill  = (const float*)d_in[5];
    const float* a_src_sj = (const float*)d_in[6];
    const float* a_dst_sj = (const float*)d_in[7];
    const float* a_src_jj = (const float*)d_in[8];
    const float* a_dst_jj = (const float*)d_in[9];
    // d_in[10], d_in[11]: a_src_js / a_dst_js — js edge-type output unused by the head; skipped.
    const float* q_vec = (const float*)d_in[12];
    const float* Wk    = (const float*)d_in[13];
    const float* bk    = (const float*)d_in[14];
    const float* W1    = (const float*)d_in[15];
    const float* b1    = (const float*)d_in[16];
    const float* W2    = (const float*)d_in[17];
    const float* b2    = (const float*)d_in[18];
    const int* ei_sj_src = (const int*)d_in[19];
    const int* ei_sj_dst = (const int*)d_in[20];
    const int* ei_jj_src = (const int*)d_in[21];
    const int* ei_jj_dst = (const int*)d_in[22];

    const int NJ   = in_sizes[0] / 256;
    const int NS   = in_sizes[1] / 256;
    const int E_sj = in_sizes[19];
    const int E_jj = in_sizes[21];
    const int gmJ  = (NJ + 127) / 128, gmS = (NS + 127) / 128;
    const long MpadJ = (long)gmJ * 128, MpadS = (long)gmS * 128;

    char* ws   = (char*)d_ws;
    size_t off = 0;
    auto alloc = [&](size_t bytes) { void* p = ws + off; off += (bytes + 255) & ~(size_t)255; return p; };
    unsigned short* h_job_bf   = (unsigned short*)alloc(MpadJ * 256 * 2);   // bf16 h tables
    unsigned short* h_skill_bf = (unsigned short*)alloc(MpadS * 256 * 2);
    unsigned short* x_job_bf   = (unsigned short*)alloc(MpadJ * 256 * 2);
    unsigned short* x_skill_bf = (unsigned short*)alloc(MpadS * 256 * 2);
    unsigned short* Wjob_t  = (unsigned short*)alloc(256 * 256 * 2);
    unsigned short* Wskl_t  = (unsigned short*)alloc(256 * 256 * 2);
    unsigned short* Wk_t    = (unsigned short*)alloc(256 * 256 * 2);
    unsigned short* W1_t    = (unsigned short*)alloc(256 * 256 * 2);
    unsigned short* out_sj_bf = (unsigned short*)alloc(MpadJ * 256 * 2);
    unsigned short* out_jj_bf = (unsigned short*)alloc(MpadJ * 256 * 2);
    float* ald_sj  = (float*)alloc((size_t)NJ * 4 * 4);
    float* als_jj  = (float*)alloc((size_t)NJ * 4 * 4);
    float* ald_jj  = (float*)alloc((size_t)NJ * 4 * 4);
    float* als_sj  = (float*)alloc((size_t)NS * 4 * 4);
    float* score  = (float*)alloc(64 * 4);   // [0..1] raw scores, [2..3] attn
    float* attn   = score + 2;
    int* deg_sj = (int*)alloc((size_t)NJ * 4);
    int* deg_jj = (int*)alloc((size_t)NJ * 4);
    int* rp_sj  = (int*)alloc(((size_t)NJ + 1) * 4);
    int* rp_jj  = (int*)alloc(((size_t)NJ + 1) * 4);
    int* part_a = (int*)alloc(1024 * 4);
    int* part_b = (int*)alloc(1024 * 4);
    int* cur_sj = (int*)alloc((size_t)NJ * 4);
    int* cur_jj = (int*)alloc((size_t)NJ * 4);
    int* csr_sj = (int*)alloc((size_t)E_sj * 4);
    int* csr_jj = (int*)alloc((size_t)E_jj * 4);
    (void)ws_size; (void)n_in;

    hipMemsetAsync(score,  0, 2 * 4, stream);
    hipMemsetAsync(deg_sj, 0, (size_t)NJ * 4, stream);
    hipMemsetAsync(deg_jj, 0, (size_t)NJ * 4, stream);
    hipMemsetAsync(cur_sj, 0, (size_t)NJ * 4, stream);
    hipMemsetAsync(cur_jj, 0, (size_t)NJ * 4, stream);

    dim3 blk(256);
    int nbJ = (NJ + SCAN_B - 1) / SCAN_B;

    // ---- casts & weight transposes ----
    long nJ = (long)NJ * 256, nJp = MpadJ * 256;
    long nS = (long)NS * 256, nSp = MpadS * 256;
    cast_pad<<<dim3((int)((nJp / 4 + 255) / 256)), blk, 0, stream>>>(x_job, x_job_bf, nJ, nJp);
    cast_pad<<<dim3((int)((nSp / 4 + 255) / 256)), blk, 0, stream>>>(x_skill, x_skill_bf, nS, nSp);
    transpose_cast<<<dim3(256), blk, 0, stream>>>(W_job, Wjob_t);
    transpose_cast<<<dim3(256), blk, 0, stream>>>(W_skill, Wskl_t);
    transpose_cast<<<dim3(256), blk, 0, stream>>>(Wk, Wk_t);
    transpose_cast<<<dim3(256), blk, 0, stream>>>(W1, W1_t);

    // ---- CSR build ----
    hist_k<<<dim3((E_sj + 255) / 256), blk, 0, stream>>>(ei_sj_dst, E_sj, deg_sj);
    hist_k<<<dim3((E_jj + 255) / 256), blk, 0, stream>>>(ei_jj_dst, E_jj, deg_jj);
    scan_bsum<<<dim3(nbJ), dim3(SCAN_B), 0, stream>>>(deg_sj, NJ, part_a);
    scan_bsum<<<dim3(nbJ), dim3(SCAN_B), 0, stream>>>(deg_jj, NJ, part_b);
    scan_part<<<dim3(1), dim3(1024), 0, stream>>>(part_a, nbJ);
    scan_part<<<dim3(1), dim3(1024), 0, stream>>>(part_b, nbJ);
    scan_final<<<dim3(nbJ), dim3(SCAN_B), 0, stream>>>(deg_sj, NJ, part_a, rp_sj, E_sj);
    scan_final<<<dim3(nbJ), dim3(SCAN_B), 0, stream>>>(deg_jj, NJ, part_b, rp_jj, E_jj);
    fill_csr<<<dim3((E_sj + 255) / 256), blk, 0, stream>>>(ei_sj_dst, E_sj, rp_sj, cur_sj, csr_sj);
    fill_csr<<<dim3((E_jj + 255) / 256), blk, 0, stream>>>(ei_jj_dst, E_jj, rp_jj, cur_jj, csr_jj);

    // ---- input projections (MFMA) + fused per-head logits, bf16 h out ----
    gemm_mfma<0, 3><<<dim3(gmJ), dim3(512), 0, stream>>>(
        x_job_bf, nullptr, Wjob_t, b_job, nullptr, nullptr, nullptr,
        h_job_bf, nullptr, nullptr,
        a_dst_sj, a_src_jj, a_dst_jj, ald_sj, als_jj, ald_jj, NJ);
    gemm_mfma<0, 1><<<dim3(gmS), dim3(512), 0, stream>>>(
        x_skill_bf, nullptr, Wskl_t, b_skill, nullptr, nullptr, nullptr,
        h_skill_bf, nullptr, nullptr,
        a_src_sj, nullptr, nullptr, als_sj, nullptr, nullptr, NS);

    // ---- fused per-dst GAT, both edge types in one launch ----
    gat_fused<<<dim3((NJ + 3) / 4, 2), blk, 0, stream>>>(
        h_skill_bf, h_job_bf, als_sj, als_jj, ald_sj, ald_jj,
        rp_sj, rp_jj, csr_sj, csr_jj, ei_sj_src, ei_jj_src, NJ,
        out_sj_bf, out_jj_bf);

    // ---- semantic attention scores (both types in one launch) ----
    gemm_mfma<1, 0><<<dim3(gmJ, 2), dim3(512), 0, stream>>>(
        out_sj_bf, out_jj_bf, Wk_t, bk, q_vec, nullptr, nullptr,
        nullptr, nullptr, score,
        nullptr, nullptr, nullptr, nullptr, nullptr, nullptr, NJ);
    attn_k<<<1, 64, 0, stream>>>(score, attn, 1.0f / (float)NJ);

    // ---- head: blend fused into A-staging; relu+W2-dot+b2 epilogue ----
    gemm_mfma<2, 0><<<dim3(gmJ), dim3(512), 0, stream>>>(
        out_sj_bf, out_jj_bf, W1_t, b1, W2, b2, attn,
        nullptr, (float*)d_out, nullptr,
        nullptr, nullptr, nullptr, nullptr, nullptr, nullptr, NJ);
}

// Round 8
// 470.071 us; speedup vs baseline: 9.8615x; 1.1364x over previous
//
#include <hip/hip_runtime.h>
#include <hip/hip_bf16.h>
#include <math.h>

#define SCAN_B 256
#define NEG_BIG (-3.0e38f)

typedef __attribute__((ext_vector_type(8))) short bf16x8;   // 8 bf16 = 4 VGPR
typedef __attribute__((ext_vector_type(4))) float f32x4;

__device__ __forceinline__ unsigned short f2bf(float f) {
    __hip_bfloat16 h = __float2bfloat16(f);   // RNE
    return *(unsigned short*)&h;
}
__device__ __forceinline__ float bf2f(unsigned short u) {
    unsigned v = ((unsigned)u) << 16;
    return __uint_as_float(v);
}
__device__ __forceinline__ float lrelu(float x) { return (x >= 0.f) ? x : 0.2f * x; }

// blend two packed bf16 pairs: r = bf16(c0*a + c1*b) lane-wise
__device__ __forceinline__ unsigned blend2(unsigned a, unsigned b, float c0, float c1) {
    float alo = bf2f((unsigned short)(a & 0xffff)), ahi = bf2f((unsigned short)(a >> 16));
    float blo = bf2f((unsigned short)(b & 0xffff)), bhi = bf2f((unsigned short)(b >> 16));
    unsigned short rlo = f2bf(c0 * alo + c1 * blo);
    unsigned short rhi = f2bf(c0 * ahi + c1 * bhi);
    return (unsigned)rlo | ((unsigned)rhi << 16);
}

// =============== MFMA GEMM: A[Mpad,256]bf16 @ B^T[256n,256k]bf16 ===============
// 128x256 tile, BK=64, 512 thr = 8 waves (2 row x 4 col of 64x64), 16x16x32 bf16.
// MODE 0: outh[M,256] = bf16(A@B + bias); fused per-head logits lo_v (head = wc)
// MODE 1: A selected by blockIdx.y; atomicAdd(scoreSlot[y], sum_rows q.tanh(A@B+bias))
// MODE 2: A' = bf16(attn0*A + attn1*A2) at stage time; outf[row] = relu-dot + b2
template<int MODE, int NV>
__launch_bounds__(512)
__global__ void gemm_mfma(const unsigned short* __restrict__ Abf,
                          const unsigned short* __restrict__ A2bf,
                          const unsigned short* __restrict__ Bt,
                          const float* __restrict__ bias,
                          const float* __restrict__ vq,
                          const float* __restrict__ b2p,
                          const float* __restrict__ attn2,
                          unsigned short* __restrict__ outh,
                          float* __restrict__ outf,
                          float* __restrict__ scoreSlot,
                          const float* __restrict__ av0,
                          const float* __restrict__ av1,
                          const float* __restrict__ av2,
                          float* __restrict__ lo0,
                          float* __restrict__ lo1,
                          float* __restrict__ lo2,
                          int M)
{
    __shared__ __align__(16) char sm[49152];   // A:[0,16K)=[128][64]bf16; B^T:[16K,48K)=[256][64]bf16
    __shared__ float red8[8];
    const int t    = threadIdx.x;
    const int lane = t & 63, wid = t >> 6;
    const int wr = wid >> 2, wc = wid & 3;
    const long row0 = (long)blockIdx.x * 128;
    const char* Ab = (const char*)((MODE == 1 && blockIdx.y == 1) ? A2bf : Abf);
    const char* A2 = (const char*)A2bf;
    const char* Bb = (const char*)Bt;

    float blend0 = 0.f, blend1 = 0.f;
    if (MODE == 2) { blend0 = attn2[0]; blend1 = attn2[1]; }

    f32x4 acc[4][4];
#pragma unroll
    for (int m = 0; m < 4; ++m)
#pragma unroll
        for (int n = 0; n < 4; ++n) acc[m][n] = (f32x4){0.f, 0.f, 0.f, 0.f};

    for (int k0 = 0; k0 < 256; k0 += 64) {
#pragma unroll
        for (int rep = 0; rep < 2; ++rep) {
            int idx = rep * 512 + t;
            int row = idx >> 3, colb = (idx & 7) << 4;
            uint4 v = *(const uint4*)(Ab + (row0 + row) * 512 + k0 * 2 + colb);
            if (MODE == 2) {
                uint4 v2 = *(const uint4*)(A2 + (row0 + row) * 512 + k0 * 2 + colb);
                v.x = blend2(v.x, v2.x, blend0, blend1);
                v.y = blend2(v.y, v2.y, blend0, blend1);
                v.z = blend2(v.z, v2.z, blend0, blend1);
                v.w = blend2(v.w, v2.w, blend0, blend1);
            }
            *(uint4*)&sm[row * 128 + (colb ^ ((row & 7) << 4))] = v;
        }
#pragma unroll
        for (int rep = 0; rep < 4; ++rep) {
            int idx = rep * 512 + t;
            int n = idx >> 3, colb = (idx & 7) << 4;
            uint4 v = *(const uint4*)(Bb + n * 512 + k0 * 2 + colb);
            *(uint4*)&sm[16384 + n * 128 + (colb ^ ((n & 7) << 4))] = v;
        }
        __syncthreads();
#pragma unroll
        for (int kki = 0; kki < 2; ++kki) {
            const int kb = kki * 64 + ((lane >> 4) << 4);
            bf16x8 a[4], b[4];
#pragma unroll
            for (int m = 0; m < 4; ++m) {
                int row = wr * 64 + m * 16 + (lane & 15);
                a[m] = *(const bf16x8*)&sm[row * 128 + (kb ^ ((row & 7) << 4))];
            }
#pragma unroll
            for (int n = 0; n < 4; ++n) {
                int nr = wc * 64 + n * 16 + (lane & 15);
                b[n] = *(const bf16x8*)&sm[16384 + nr * 128 + (kb ^ ((nr & 7) << 4))];
            }
#pragma unroll
            for (int m = 0; m < 4; ++m)
#pragma unroll
                for (int n = 0; n < 4; ++n)
                    acc[m][n] = __builtin_amdgcn_mfma_f32_16x16x32_bf16(a[m], b[n], acc[m][n], 0, 0, 0);
        }
        __syncthreads();
    }

    const int colbase = wc * 64 + (lane & 15);
    const int rbase   = wr * 64 + ((lane >> 4) << 2);
    float bv[4];
#pragma unroll
    for (int n = 0; n < 4; ++n) bv[n] = bias[colbase + n * 16];

    if (MODE == 0) {
        float areg[(NV > 0) ? NV : 1][4];
#pragma unroll
        for (int v = 0; v < NV; ++v) {
            const float* av = (v == 0) ? av0 : (v == 1) ? av1 : av2;
#pragma unroll
            for (int n = 0; n < 4; ++n) areg[v][n] = av[colbase + n * 16];
        }
#pragma unroll
        for (int m = 0; m < 4; ++m) {
#pragma unroll
            for (int j = 0; j < 4; ++j) {
                long row = row0 + rbase + m * 16 + j;
                float hv[4];
#pragma unroll
                for (int n = 0; n < 4; ++n) hv[n] = acc[m][n][j] + bv[n];
                if (row < M) {
#pragma unroll
                    for (int n = 0; n < 4; ++n)
                        outh[row * 256 + colbase + n * 16] = f2bf(hv[n]);
                }
#pragma unroll
                for (int v = 0; v < NV; ++v) {
                    float p = hv[0] * areg[v][0] + hv[1] * areg[v][1]
                            + hv[2] * areg[v][2] + hv[3] * areg[v][3];
                    p += __shfl_xor(p, 1); p += __shfl_xor(p, 2);
                    p += __shfl_xor(p, 4); p += __shfl_xor(p, 8);
                    if ((lane & 15) == 0 && row < M) {
                        float* lo = (v == 0) ? lo0 : (v == 1) ? lo1 : lo2;
                        lo[row * 4 + wc] = p;
                    }
                }
            }
        }
    } else if (MODE == 1) {
        float p = 0.f;
        float qv[4];
#pragma unroll
        for (int n = 0; n < 4; ++n) qv[n] = vq[colbase + n * 16];
#pragma unroll
        for (int n = 0; n < 4; ++n) {
#pragma unroll
            for (int m = 0; m < 4; ++m) {
                long row = row0 + rbase + m * 16;
#pragma unroll
                for (int j = 0; j < 4; ++j)
                    if (row + j < M) p += qv[n] * tanhf(acc[m][n][j] + bv[n]);
            }
        }
#pragma unroll
        for (int off = 32; off > 0; off >>= 1) p += __shfl_xor(p, off);
        if (lane == 0) red8[wid] = p;
        __syncthreads();
        if (t == 0) {
            float s = 0.f;
#pragma unroll
            for (int i = 0; i < 8; ++i) s += red8[i];
            atomicAdd(&scoreSlot[blockIdx.y], s);
        }
    } else {
        float* redC = (float*)sm;   // reuse tile buffer (free after final barrier)
        float b2v = b2p[0];
        float wv[4];
#pragma unroll
        for (int n = 0; n < 4; ++n) wv[n] = vq[colbase + n * 16];
#pragma unroll
        for (int m = 0; m < 4; ++m) {
#pragma unroll
            for (int j = 0; j < 4; ++j) {
                float s = 0.f;
#pragma unroll
                for (int n = 0; n < 4; ++n)
                    s += fmaxf(acc[m][n][j] + bv[n], 0.f) * wv[n];
                s += __shfl_xor(s, 1); s += __shfl_xor(s, 2);
                s += __shfl_xor(s, 4); s += __shfl_xor(s, 8);
                if ((lane & 15) == 0) {
                    int lrow = wr * 64 + m * 16 + ((lane >> 4) << 2) + j;
                    redC[lrow * 4 + wc] = s;
                }
            }
        }
        __syncthreads();
        if (t < 128) {
            long row = row0 + t;
            if (row < M)
                outf[row] = redC[t * 4 + 0] + redC[t * 4 + 1]
                          + redC[t * 4 + 2] + redC[t * 4 + 3] + b2v;
        }
    }
}

// ---------------- casts / transposes ----------------
__global__ void cast_pad(const float* __restrict__ src, unsigned short* __restrict__ dst,
                         long n, long npad)
{
    long i = ((long)blockIdx.x * 256 + threadIdx.x) * 4;
    if (i >= npad) return;
    ushort4 o;
    if (i + 4 <= n) {
        float4 v = *(const float4*)&src[i];
        o.x = f2bf(v.x); o.y = f2bf(v.y); o.z = f2bf(v.z); o.w = f2bf(v.w);
    } else {
        float vv[4];
#pragma unroll
        for (int j = 0; j < 4; ++j) vv[j] = (i + j < n) ? src[i + j] : 0.f;
        o.x = f2bf(vv[0]); o.y = f2bf(vv[1]); o.z = f2bf(vv[2]); o.w = f2bf(vv[3]);
    }
    *(ushort4*)&dst[i] = o;
}

__global__ void transpose_cast(const float* __restrict__ W, unsigned short* __restrict__ Wt)
{   // Wt[n][k] = bf16(W[k][n]); 256x256
    int n = blockIdx.x, k = threadIdx.x;
    Wt[n * 256 + k] = f2bf(W[k * 256 + n]);
}

// ---------------- CSR build (both edge types via blockIdx.y) ----------------
__global__ void hist2(const int* __restrict__ d0, int E0, int* __restrict__ g0,
                      const int* __restrict__ d1, int E1, int* __restrict__ g1)
{
    int e = blockIdx.x * 256 + threadIdx.x;
    if (blockIdx.y == 0) { if (e < E0) atomicAdd(&g0[d0[e]], 1); }
    else                 { if (e < E1) atomicAdd(&g1[d1[e]], 1); }
}

__global__ void scan_bsum2(const int* __restrict__ g0, const int* __restrict__ g1, int n,
                           int* __restrict__ p0, int* __restrict__ p1)
{
    const int* deg = blockIdx.y ? g1 : g0;
    int* part      = blockIdx.y ? p1 : p0;
    __shared__ int smem[SCAN_B];
    int i = blockIdx.x * SCAN_B + threadIdx.x;
    smem[threadIdx.x] = (i < n) ? deg[i] : 0;
    __syncthreads();
    for (int off = SCAN_B / 2; off > 0; off >>= 1) {
        if (threadIdx.x < off) smem[threadIdx.x] += smem[threadIdx.x + off];
        __syncthreads();
    }
    if (threadIdx.x == 0) part[blockIdx.x] = smem[0];
}

__global__ void scan_part2(int* __restrict__ p0, int* __restrict__ p1, int nb)
{
    int* part = blockIdx.y ? p1 : p0;
    __shared__ int smem[1024];
    int t = threadIdx.x;
    int v = (t < nb) ? part[t] : 0;
    smem[t] = v;
    __syncthreads();
    for (int off = 1; off < 1024; off <<= 1) {
        int add = (t >= off) ? smem[t - off] : 0;
        __syncthreads();
        smem[t] += add;
        __syncthreads();
    }
    if (t < nb) part[t] = smem[t] - v;
}

__global__ void scan_final2(const int* __restrict__ g0, const int* __restrict__ g1, int n,
                            const int* __restrict__ p0, const int* __restrict__ p1,
                            int* __restrict__ r0, int* __restrict__ r1, int E0, int E1)
{
    const int* deg = blockIdx.y ? g1 : g0;
    const int* part = blockIdx.y ? p1 : p0;
    int* rowptr = blockIdx.y ? r1 : r0;
    int E = blockIdx.y ? E1 : E0;
    __shared__ int smem[SCAN_B];
    int t = threadIdx.x;
    int i = blockIdx.x * SCAN_B + t;
    int v = (i < n) ? deg[i] : 0;
    smem[t] = v;
    __syncthreads();
    for (int off = 1; off < SCAN_B; off <<= 1) {
        int add = (t >= off) ? smem[t - off] : 0;
        __syncthreads();
        smem[t] += add;
        __syncthreads();
    }
    if (i < n) rowptr[i] = part[blockIdx.x] + smem[t] - v;
    if (blockIdx.x == 0 && t == 0) rowptr[n] = E;
}

__global__ void fill_csr2(const int* __restrict__ d0, int E0, const int* __restrict__ r0,
                          int* __restrict__ c0, int* __restrict__ o0,
                          const int* __restrict__ d1, int E1, const int* __restrict__ r1,
                          int* __restrict__ c1, int* __restrict__ o1)
{
    int e = blockIdx.x * 256 + threadIdx.x;
    if (blockIdx.y == 0) {
        if (e < E0) { int d = d0[e]; int s = atomicAdd(&c0[d], 1); o0[r0[d] + s] = e; }
    } else {
        if (e < E1) { int d = d1[e]; int s = atomicAdd(&c1[d], 1); o1[r1[d] + s] = e; }
    }
}

// ======== fused per-dst GAT (merged over gridDim.y = 2 edge types) ========
// one wave per dst node; bf16 x tables; softmax in-wave; gather batched x4 for MLP.
__launch_bounds__(256)
__global__ void gat_fused(const unsigned short* __restrict__ xs0,
                          const unsigned short* __restrict__ xs1,
                          const float* __restrict__ als0, const float* __restrict__ als1,
                          const float* __restrict__ ald0, const float* __restrict__ ald1,
                          const int* __restrict__ rp0, const int* __restrict__ rp1,
                          const int* __restrict__ csr0, const int* __restrict__ csr1,
                          const int* __restrict__ src0, const int* __restrict__ src1,
                          int N,
                          unsigned short* __restrict__ out0,
                          unsigned short* __restrict__ out1)
{
    const int et = blockIdx.y;
    const unsigned short* xsrc = et ? xs1 : xs0;
    const float* als = et ? als1 : als0;
    const float* ald = et ? ald1 : ald0;
    const int* rowptr = et ? rp1 : rp0;
    const int* csr    = et ? csr1 : csr0;
    const int* src    = et ? src1 : src0;
    unsigned short* outb = et ? out1 : out0;

    __shared__ float lw[4][64 * 4];
    __shared__ int   ls[4][64];
    const int wv   = threadIdx.x >> 6;
    const int w    = (int)((blockIdx.x * 256 + threadIdx.x) >> 6);
    const int lane = threadIdx.x & 63;
    if (w >= N) return;
    const int beg = rowptr[w], end = rowptr[w + 1];
    const int deg = end - beg;
    const int h = lane >> 4;
    const float4 d4 = *(const float4*)&ald[(size_t)w * 4];
    const size_t loff = (size_t)(lane << 2);

    float4 accA = make_float4(0.f, 0.f, 0.f, 0.f);
    float4 accB = make_float4(0.f, 0.f, 0.f, 0.f);
    float dn0 = 0.f, dn1 = 0.f, dn2 = 0.f, dn3 = 0.f;

    if (deg <= 64) {
        float al0 = NEG_BIG, al1 = NEG_BIG, al2 = NEG_BIG, al3 = NEG_BIG;
        int es = 0;
        if (lane < deg) {
            int e = csr[beg + lane];
            es = src[e];
            float4 a = *(const float4*)&als[(size_t)es * 4];
            al0 = lrelu(a.x + d4.x); al1 = lrelu(a.y + d4.y);
            al2 = lrelu(a.z + d4.z); al3 = lrelu(a.w + d4.w);
        }
        float m0 = al0, m1 = al1, m2 = al2, m3 = al3;
#pragma unroll
        for (int off = 32; off > 0; off >>= 1) {
            m0 = fmaxf(m0, __shfl_xor(m0, off));
            m1 = fmaxf(m1, __shfl_xor(m1, off));
            m2 = fmaxf(m2, __shfl_xor(m2, off));
            m3 = fmaxf(m3, __shfl_xor(m3, off));
        }
        float w0 = 0.f, w1 = 0.f, w2 = 0.f, w3 = 0.f;
        if (lane < deg) {
            w0 = expf(al0 - m0); w1 = expf(al1 - m1);
            w2 = expf(al2 - m2); w3 = expf(al3 - m3);
            ls[wv][lane] = es;
            lw[wv][lane * 4 + 0] = w0; lw[wv][lane * 4 + 1] = w1;
            lw[wv][lane * 4 + 2] = w2; lw[wv][lane * 4 + 3] = w3;
        }
        dn0 = w0; dn1 = w1; dn2 = w2; dn3 = w3;

        // ---- batched gather: 4 rows in flight per iteration ----
        int i = 0;
        for (; i + 4 <= deg; i += 4) {
            int s0 = ls[wv][i + 0], s1 = ls[wv][i + 1];
            int s2 = ls[wv][i + 2], s3 = ls[wv][i + 3];
            float wx0 = lw[wv][(i + 0) * 4 + h], wx1 = lw[wv][(i + 1) * 4 + h];
            float wx2 = lw[wv][(i + 2) * 4 + h], wx3 = lw[wv][(i + 3) * 4 + h];
            ushort4 x0 = *(const ushort4*)&xsrc[(size_t)s0 * 256 + loff];
            ushort4 x1 = *(const ushort4*)&xsrc[(size_t)s1 * 256 + loff];
            ushort4 x2 = *(const ushort4*)&xsrc[(size_t)s2 * 256 + loff];
            ushort4 x3 = *(const ushort4*)&xsrc[(size_t)s3 * 256 + loff];
            accA.x += wx0 * bf2f(x0.x); accA.y += wx0 * bf2f(x0.y);
            accA.z += wx0 * bf2f(x0.z); accA.w += wx0 * bf2f(x0.w);
            accB.x += wx1 * bf2f(x1.x); accB.y += wx1 * bf2f(x1.y);
            accB.z += wx1 * bf2f(x1.z); accB.w += wx1 * bf2f(x1.w);
            accA.x += wx2 * bf2f(x2.x); accA.y += wx2 * bf2f(x2.y);
            accA.z += wx2 * bf2f(x2.z); accA.w += wx2 * bf2f(x2.w);
            accB.x += wx3 * bf2f(x3.x); accB.y += wx3 * bf2f(x3.y);
            accB.z += wx3 * bf2f(x3.z); accB.w += wx3 * bf2f(x3.w);
        }
        for (; i < deg; ++i) {
            int s = ls[wv][i];
            float wx = lw[wv][i * 4 + h];
            ushort4 xu = *(const ushort4*)&xsrc[(size_t)s * 256 + loff];
            accA.x += wx * bf2f(xu.x); accA.y += wx * bf2f(xu.y);
            accA.z += wx * bf2f(xu.z); accA.w += wx * bf2f(xu.w);
        }
    } else {
        // general path (rare): pass 1 = global max, pass 2 = exp + gather
        float m0 = NEG_BIG, m1 = NEG_BIG, m2 = NEG_BIG, m3 = NEG_BIG;
        for (int c = beg; c < end; c += 64) {
            if (c + lane < end) {
                int e = csr[c + lane];
                int s = src[e];
                float4 a = *(const float4*)&als[(size_t)s * 4];
                m0 = fmaxf(m0, lrelu(a.x + d4.x)); m1 = fmaxf(m1, lrelu(a.y + d4.y));
                m2 = fmaxf(m2, lrelu(a.z + d4.z)); m3 = fmaxf(m3, lrelu(a.w + d4.w));
            }
        }
#pragma unroll
        for (int off = 32; off > 0; off >>= 1) {
            m0 = fmaxf(m0, __shfl_xor(m0, off));
            m1 = fmaxf(m1, __shfl_xor(m1, off));
            m2 = fmaxf(m2, __shfl_xor(m2, off));
            m3 = fmaxf(m3, __shfl_xor(m3, off));
        }
        for (int c = beg; c < end; c += 64) {
            int cnt = min(64, end - c);
            if (lane < cnt) {
                int e = csr[c + lane];
                int es = src[e];
                float4 a = *(const float4*)&als[(size_t)es * 4];
                float w0 = expf(lrelu(a.x + d4.x) - m0);
                float w1 = expf(lrelu(a.y + d4.y) - m1);
                float w2 = expf(lrelu(a.z + d4.z) - m2);
                float w3 = expf(lrelu(a.w + d4.w) - m3);
                ls[wv][lane] = es;
                lw[wv][lane * 4 + 0] = w0; lw[wv][lane * 4 + 1] = w1;
                lw[wv][lane * 4 + 2] = w2; lw[wv][lane * 4 + 3] = w3;
                dn0 += w0; dn1 += w1; dn2 += w2; dn3 += w3;
            }
            int i = 0;
            for (; i + 4 <= cnt; i += 4) {
                int s0 = ls[wv][i + 0], s1 = ls[wv][i + 1];
                int s2 = ls[wv][i + 2], s3 = ls[wv][i + 3];
                float wx0 = lw[wv][(i + 0) * 4 + h], wx1 = lw[wv][(i + 1) * 4 + h];
                float wx2 = lw[wv][(i + 2) * 4 + h], wx3 = lw[wv][(i + 3) * 4 + h];
                ushort4 x0 = *(const ushort4*)&xsrc[(size_t)s0 * 256 + loff];
                ushort4 x1 = *(const ushort4*)&xsrc[(size_t)s1 * 256 + loff];
                ushort4 x2 = *(const ushort4*)&xsrc[(size_t)s2 * 256 + loff];
                ushort4 x3 = *(const ushort4*)&xsrc[(size_t)s3 * 256 + loff];
                accA.x += wx0 * bf2f(x0.x); accA.y += wx0 * bf2f(x0.y);
                accA.z += wx0 * bf2f(x0.z); accA.w += wx0 * bf2f(x0.w);
                accB.x += wx1 * bf2f(x1.x); accB.y += wx1 * bf2f(x1.y);
                accB.z += wx1 * bf2f(x1.z); accB.w += wx1 * bf2f(x1.w);
                accA.x += wx2 * bf2f(x2.x); accA.y += wx2 * bf2f(x2.y);
                accA.z += wx2 * bf2f(x2.z); accA.w += wx2 * bf2f(x2.w);
                accB.x += wx3 * bf2f(x3.x); accB.y += wx3 * bf2f(x3.y);
                accB.z += wx3 * bf2f(x3.z); accB.w += wx3 * bf2f(x3.w);
            }
            for (; i < cnt; ++i) {
                int s = ls[wv][i];
                float wx = lw[wv][i * 4 + h];
                ushort4 xu = *(const ushort4*)&xsrc[(size_t)s * 256 + loff];
                accA.x += wx * bf2f(xu.x); accA.y += wx * bf2f(xu.y);
                accA.z += wx * bf2f(xu.z); accA.w += wx * bf2f(xu.w);
            }
        }
    }

    float4 acc = make_float4(accA.x + accB.x, accA.y + accB.y,
                             accA.z + accB.z, accA.w + accB.w);
#pragma unroll
    for (int off = 32; off > 0; off >>= 1) {
        dn0 += __shfl_xor(dn0, off);
        dn1 += __shfl_xor(dn1, off);
        dn2 += __shfl_xor(dn2, off);
        dn3 += __shfl_xor(dn3, off);
    }
    float dh = (h == 0) ? dn0 : (h == 1) ? dn1 : (h == 2) ? dn2 : dn3;
    float inv = 1.f / (dh + 1e-16f);
    ushort4 uo;
    uo.x = f2bf(fmaxf(acc.x * inv, 0.f));
    uo.y = f2bf(fmaxf(acc.y * inv, 0.f));
    uo.z = f2bf(fmaxf(acc.z * inv, 0.f));
    uo.w = f2bf(fmaxf(acc.w * inv, 0.f));
    *(ushort4*)&outb[(size_t)w * 256 + loff] = uo;
}

__global__ void attn_k(const float* __restrict__ score, float* __restrict__ attn, float invN)
{
    if (threadIdx.x == 0 && blockIdx.x == 0) {
        float s0 = score[0] * invN, s1 = score[1] * invN;
        float m  = fmaxf(s0, s1);
        float e0 = expf(s0 - m), e1 = expf(s1 - m);
        float dsum = e0 + e1;
        attn[0] = e0 / dsum;
        attn[1] = e1 / dsum;
    }
}

extern "C" void kernel_launch(void* const* d_in, const int* in_sizes, int n_in,
                              void* d_out, int out_size, void* d_ws, size_t ws_size,
                              hipStream_t stream)
{
    const float* x_job    = (const float*)d_in[0];
    const float* x_skill  = (const float*)d_in[1];
    const float* W_job    = (const float*)d_in[2];
    const float* b_job    = (const float*)d_in[3];
    const float* W_skill  = (const float*)d_in[4];
    const float* b_skill  = (const float*)d_in[5];
    const float* a_src_sj = (const float*)d_in[6];
    const float* a_dst_sj = (const float*)d_in[7];
    const float* a_src_jj = (const float*)d_in[8];
    const float* a_dst_jj = (const float*)d_in[9];
    // d_in[10], d_in[11]: a_src_js / a_dst_js — js edge-type output unused by the head; skipped.
    const float* q_vec = (const float*)d_in[12];
    const float* Wk    = (const float*)d_in[13];
    const float* bk    = (const float*)d_in[14];
    const float* W1    = (const float*)d_in[15];
    const float* b1    = (const float*)d_in[16];
    const float* W2    = (const float*)d_in[17];
    const float* b2    = (const float*)d_in[18];
    const int* ei_sj_src = (const int*)d_in[19];
    const int* ei_sj_dst = (const int*)d_in[20];
    const int* ei_jj_src = (const int*)d_in[21];
    const int* ei_jj_dst = (const int*)d_in[22];

    const int NJ   = in_sizes[0] / 256;
    const int NS   = in_sizes[1] / 256;
    const int E_sj = in_sizes[19];
    const int E_jj = in_sizes[21];
    const int Emax = (E_sj > E_jj) ? E_sj : E_jj;
    const int gmJ  = (NJ + 127) / 128, gmS = (NS + 127) / 128;
    const long MpadJ = (long)gmJ * 128, MpadS = (long)gmS * 128;

    char* ws   = (char*)d_ws;
    size_t off = 0;
    auto alloc = [&](size_t bytes) { void* p = ws + off; off += (bytes + 255) & ~(size_t)255; return p; };
    unsigned short* h_job_bf   = (unsigned short*)alloc(MpadJ * 256 * 2);   // bf16 h tables
    unsigned short* h_skill_bf = (unsigned short*)alloc(MpadS * 256 * 2);
    unsigned short* x_job_bf   = (unsigned short*)alloc(MpadJ * 256 * 2);
    unsigned short* x_skill_bf = (unsigned short*)alloc(MpadS * 256 * 2);
    unsigned short* Wjob_t  = (unsigned short*)alloc(256 * 256 * 2);
    unsigned short* Wskl_t  = (unsigned short*)alloc(256 * 256 * 2);
    unsigned short* Wk_t    = (unsigned short*)alloc(256 * 256 * 2);
    unsigned short* W1_t    = (unsigned short*)alloc(256 * 256 * 2);
    unsigned short* out_sj_bf = (unsigned short*)alloc(MpadJ * 256 * 2);
    unsigned short* out_jj_bf = (unsigned short*)alloc(MpadJ * 256 * 2);
    float* ald_sj  = (float*)alloc((size_t)NJ * 4 * 4);
    float* als_jj  = (float*)alloc((size_t)NJ * 4 * 4);
    float* ald_jj  = (float*)alloc((size_t)NJ * 4 * 4);
    float* als_sj  = (float*)alloc((size_t)NS * 4 * 4);
    float* score  = (float*)alloc(64 * 4);   // [0..1] raw scores, [2..3] attn
    float* attn   = score + 2;
    int* deg_sj = (int*)alloc((size_t)NJ * 4);
    int* deg_jj = (int*)alloc((size_t)NJ * 4);
    int* rp_sj  = (int*)alloc(((size_t)NJ + 1) * 4);
    int* rp_jj  = (int*)alloc(((size_t)NJ + 1) * 4);
    int* part_a = (int*)alloc(1024 * 4);
    int* part_b = (int*)alloc(1024 * 4);
    int* cur_sj = (int*)alloc((size_t)NJ * 4);
    int* cur_jj = (int*)alloc((size_t)NJ * 4);
    int* csr_sj = (int*)alloc((size_t)E_sj * 4);
    int* csr_jj = (int*)alloc((size_t)E_jj * 4);
    (void)ws_size; (void)n_in;

    hipMemsetAsync(score,  0, 2 * 4, stream);
    hipMemsetAsync(deg_sj, 0, (size_t)NJ * 4, stream);
    hipMemsetAsync(deg_jj, 0, (size_t)NJ * 4, stream);
    hipMemsetAsync(cur_sj, 0, (size_t)NJ * 4, stream);
    hipMemsetAsync(cur_jj, 0, (size_t)NJ * 4, stream);

    dim3 blk(256);
    int nbJ = (NJ + SCAN_B - 1) / SCAN_B;

    // ---- casts & weight transposes ----
    long nJ = (long)NJ * 256, nJp = MpadJ * 256;
    long nS = (long)NS * 256, nSp = MpadS * 256;
    cast_pad<<<dim3((int)((nJp / 4 + 255) / 256)), blk, 0, stream>>>(x_job, x_job_bf, nJ, nJp);
    cast_pad<<<dim3((int)((nSp / 4 + 255) / 256)), blk, 0, stream>>>(x_skill, x_skill_bf, nS, nSp);
    transpose_cast<<<dim3(256), blk, 0, stream>>>(W_job, Wjob_t);
    transpose_cast<<<dim3(256), blk, 0, stream>>>(W_skill, Wskl_t);
    transpose_cast<<<dim3(256), blk, 0, stream>>>(Wk, Wk_t);
    transpose_cast<<<dim3(256), blk, 0, stream>>>(W1, W1_t);

    // ---- CSR build (merged pairs) ----
    hist2<<<dim3((Emax + 255) / 256, 2), blk, 0, stream>>>(
        ei_sj_dst, E_sj, deg_sj, ei_jj_dst, E_jj, deg_jj);
    scan_bsum2<<<dim3(nbJ, 2), dim3(SCAN_B), 0, stream>>>(deg_sj, deg_jj, NJ, part_a, part_b);
    scan_part2<<<dim3(1, 2), dim3(1024), 0, stream>>>(part_a, part_b, nbJ);
    scan_final2<<<dim3(nbJ, 2), dim3(SCAN_B), 0, stream>>>(
        deg_sj, deg_jj, NJ, part_a, part_b, rp_sj, rp_jj, E_sj, E_jj);
    fill_csr2<<<dim3((Emax + 255) / 256, 2), blk, 0, stream>>>(
        ei_sj_dst, E_sj, rp_sj, cur_sj, csr_sj,
        ei_jj_dst, E_jj, rp_jj, cur_jj, csr_jj);

    // ---- input projections (MFMA) + fused per-head logits, bf16 h out ----
    gemm_mfma<0, 3><<<dim3(gmJ), dim3(512), 0, stream>>>(
        x_job_bf, nullptr, Wjob_t, b_job, nullptr, nullptr, nullptr,
        h_job_bf, nullptr, nullptr,
        a_dst_sj, a_src_jj, a_dst_jj, ald_sj, als_jj, ald_jj, NJ);
    gemm_mfma<0, 1><<<dim3(gmS), dim3(512), 0, stream>>>(
        x_skill_bf, nullptr, Wskl_t, b_skill, nullptr, nullptr, nullptr,
        h_skill_bf, nullptr, nullptr,
        a_src_sj, nullptr, nullptr, als_sj, nullptr, nullptr, NS);

    // ---- fused per-dst GAT, both edge types in one launch ----
    gat_fused<<<dim3((NJ + 3) / 4, 2), blk, 0, stream>>>(
        h_skill_bf, h_job_bf, als_sj, als_jj, ald_sj, ald_jj,
        rp_sj, rp_jj, csr_sj, csr_jj, ei_sj_src, ei_jj_src, NJ,
        out_sj_bf, out_jj_bf);

    // ---- semantic attention scores (both types in one launch) ----
    gemm_mfma<1, 0><<<dim3(gmJ, 2), dim3(512), 0, stream>>>(
        out_sj_bf, out_jj_bf, Wk_t, bk, q_vec, nullptr, nullptr,
        nullptr, nullptr, score,
        nullptr, nullptr, nullptr, nullptr, nullptr, nullptr, NJ);
    attn_k<<<1, 64, 0, stream>>>(score, attn, 1.0f / (float)NJ);

    // ---- head: blend fused into A-staging; relu+W2-dot+b2 epilogue ----
    gemm_mfma<2, 0><<<dim3(gmJ), dim3(512), 0, stream>>>(
        out_sj_bf, out_jj_bf, W1_t, b1, W2, b2, attn,
        nullptr, (float*)d_out, nullptr,
        nullptr, nullptr, nullptr, nullptr, nullptr, nullptr, NJ);
}

// Round 9
// 466.599 us; speedup vs baseline: 9.9349x; 1.0074x over previous
//
#include <hip/hip_runtime.h>
#include <hip/hip_bf16.h>
#include <math.h>

#define SCAN_B 256
#define NEG_BIG (-3.0e38f)

typedef __attribute__((ext_vector_type(8))) short bf16x8;   // 8 bf16 = 4 VGPR
typedef __attribute__((ext_vector_type(4))) float f32x4;

__device__ __forceinline__ unsigned short f2bf(float f) {
    __hip_bfloat16 h = __float2bfloat16(f);   // RNE
    return *(unsigned short*)&h;
}
__device__ __forceinline__ float bf2f(unsigned short u) {
    unsigned v = ((unsigned)u) << 16;
    return __uint_as_float(v);
}
__device__ __forceinline__ float lrelu(float x) { return (x >= 0.f) ? x : 0.2f * x; }

// blend two packed bf16 pairs: r = bf16(c0*a + c1*b) lane-wise
__device__ __forceinline__ unsigned blend2(unsigned a, unsigned b, float c0, float c1) {
    float alo = bf2f((unsigned short)(a & 0xffff)), ahi = bf2f((unsigned short)(a >> 16));
    float blo = bf2f((unsigned short)(b & 0xffff)), bhi = bf2f((unsigned short)(b >> 16));
    unsigned short rlo = f2bf(c0 * alo + c1 * blo);
    unsigned short rhi = f2bf(c0 * ahi + c1 * bhi);
    return (unsigned)rlo | ((unsigned)rhi << 16);
}

// acc[0..7] += w * bf16x8(u)   (u = 4 dwords, 2 bf16 each)
__device__ __forceinline__ void fma8(float* a, uint4 u, float w) {
    a[0] += w * __uint_as_float(u.x << 16);
    a[1] += w * __uint_as_float(u.x & 0xffff0000u);
    a[2] += w * __uint_as_float(u.y << 16);
    a[3] += w * __uint_as_float(u.y & 0xffff0000u);
    a[4] += w * __uint_as_float(u.z << 16);
    a[5] += w * __uint_as_float(u.z & 0xffff0000u);
    a[6] += w * __uint_as_float(u.w << 16);
    a[7] += w * __uint_as_float(u.w & 0xffff0000u);
}

// =============== MFMA GEMM: A[*,256] @ B^T[256n,256k]bf16 ===============
// 128x256 tile, BK=64, 512 thr = 8 waves (2 row x 4 col of 64x64), 16x16x32 bf16.
// AF32: A is f32, converted to bf16 during LDS staging (fuses the cast kernel).
// MODE 0: outh[M,256] = bf16(A@B + bias); fused per-head logits lo_v (head = wc)
// MODE 1: A selected by blockIdx.y; atomicAdd(scoreSlot[y], sum_rows q.tanh(A@B+bias))
// MODE 2: A' = bf16(attn0*A + attn1*A2) at stage time; outf[row] = relu-dot + b2
template<int MODE, int NV, int AF32>
__launch_bounds__(512)
__global__ void gemm_mfma(const float* __restrict__ Af32,
                          const unsigned short* __restrict__ Abf,
                          const unsigned short* __restrict__ A2bf,
                          const unsigned short* __restrict__ Bt,
                          const float* __restrict__ bias,
                          const float* __restrict__ vq,
                          const float* __restrict__ b2p,
                          const float* __restrict__ attn2,
                          unsigned short* __restrict__ outh,
                          float* __restrict__ outf,
                          float* __restrict__ scoreSlot,
                          const float* __restrict__ av0,
                          const float* __restrict__ av1,
                          const float* __restrict__ av2,
                          float* __restrict__ lo0,
                          float* __restrict__ lo1,
                          float* __restrict__ lo2,
                          int M)
{
    __shared__ __align__(16) char sm[49152];   // A:[0,16K)=[128][64]bf16; B^T:[16K,48K)=[256][64]bf16
    __shared__ float red8[8];
    const int t    = threadIdx.x;
    const int lane = t & 63, wid = t >> 6;
    const int wr = wid >> 2, wc = wid & 3;
    const long row0 = (long)blockIdx.x * 128;
    const char* Ab = (const char*)((MODE == 1 && blockIdx.y == 1) ? A2bf : Abf);
    const char* A2 = (const char*)A2bf;
    const char* Bb = (const char*)Bt;

    float blend0 = 0.f, blend1 = 0.f;
    if (MODE == 2) { blend0 = attn2[0]; blend1 = attn2[1]; }

    f32x4 acc[4][4];
#pragma unroll
    for (int m = 0; m < 4; ++m)
#pragma unroll
        for (int n = 0; n < 4; ++n) acc[m][n] = (f32x4){0.f, 0.f, 0.f, 0.f};

    for (int k0 = 0; k0 < 256; k0 += 64) {
#pragma unroll
        for (int rep = 0; rep < 2; ++rep) {
            int idx = rep * 512 + t;
            int row = idx >> 3, colb = (idx & 7) << 4;
            uint4 v;
            if (AF32) {
                long grow = row0 + row;
                if (grow < M) {
                    const float* sp = Af32 + grow * 256 + k0 + ((idx & 7) << 3);
                    float4 f0 = *(const float4*)sp;
                    float4 f1 = *(const float4*)(sp + 4);
                    v.x = (unsigned)f2bf(f0.x) | ((unsigned)f2bf(f0.y) << 16);
                    v.y = (unsigned)f2bf(f0.z) | ((unsigned)f2bf(f0.w) << 16);
                    v.z = (unsigned)f2bf(f1.x) | ((unsigned)f2bf(f1.y) << 16);
                    v.w = (unsigned)f2bf(f1.z) | ((unsigned)f2bf(f1.w) << 16);
                } else {
                    v = make_uint4(0u, 0u, 0u, 0u);
                }
            } else {
                v = *(const uint4*)(Ab + (row0 + row) * 512 + k0 * 2 + colb);
                if (MODE == 2) {
                    uint4 v2 = *(const uint4*)(A2 + (row0 + row) * 512 + k0 * 2 + colb);
                    v.x = blend2(v.x, v2.x, blend0, blend1);
                    v.y = blend2(v.y, v2.y, blend0, blend1);
                    v.z = blend2(v.z, v2.z, blend0, blend1);
                    v.w = blend2(v.w, v2.w, blend0, blend1);
                }
            }
            *(uint4*)&sm[row * 128 + (colb ^ ((row & 7) << 4))] = v;
        }
#pragma unroll
        for (int rep = 0; rep < 4; ++rep) {
            int idx = rep * 512 + t;
            int n = idx >> 3, colb = (idx & 7) << 4;
            uint4 v = *(const uint4*)(Bb + n * 512 + k0 * 2 + colb);
            *(uint4*)&sm[16384 + n * 128 + (colb ^ ((n & 7) << 4))] = v;
        }
        __syncthreads();
#pragma unroll
        for (int kki = 0; kki < 2; ++kki) {
            const int kb = kki * 64 + ((lane >> 4) << 4);
            bf16x8 a[4], b[4];
#pragma unroll
            for (int m = 0; m < 4; ++m) {
                int row = wr * 64 + m * 16 + (lane & 15);
                a[m] = *(const bf16x8*)&sm[row * 128 + (kb ^ ((row & 7) << 4))];
            }
#pragma unroll
            for (int n = 0; n < 4; ++n) {
                int nr = wc * 64 + n * 16 + (lane & 15);
                b[n] = *(const bf16x8*)&sm[16384 + nr * 128 + (kb ^ ((nr & 7) << 4))];
            }
#pragma unroll
            for (int m = 0; m < 4; ++m)
#pragma unroll
                for (int n = 0; n < 4; ++n)
                    acc[m][n] = __builtin_amdgcn_mfma_f32_16x16x32_bf16(a[m], b[n], acc[m][n], 0, 0, 0);
        }
        __syncthreads();
    }

    const int colbase = wc * 64 + (lane & 15);
    const int rbase   = wr * 64 + ((lane >> 4) << 2);
    float bv[4];
#pragma unroll
    for (int n = 0; n < 4; ++n) bv[n] = bias[colbase + n * 16];

    if (MODE == 0) {
        float areg[(NV > 0) ? NV : 1][4];
#pragma unroll
        for (int v = 0; v < NV; ++v) {
            const float* av = (v == 0) ? av0 : (v == 1) ? av1 : av2;
#pragma unroll
            for (int n = 0; n < 4; ++n) areg[v][n] = av[colbase + n * 16];
        }
#pragma unroll
        for (int m = 0; m < 4; ++m) {
#pragma unroll
            for (int j = 0; j < 4; ++j) {
                long row = row0 + rbase + m * 16 + j;
                float hv[4];
#pragma unroll
                for (int n = 0; n < 4; ++n) hv[n] = acc[m][n][j] + bv[n];
                if (row < M) {
#pragma unroll
                    for (int n = 0; n < 4; ++n)
                        outh[row * 256 + colbase + n * 16] = f2bf(hv[n]);
                }
#pragma unroll
                for (int v = 0; v < NV; ++v) {
                    float p = hv[0] * areg[v][0] + hv[1] * areg[v][1]
                            + hv[2] * areg[v][2] + hv[3] * areg[v][3];
                    p += __shfl_xor(p, 1); p += __shfl_xor(p, 2);
                    p += __shfl_xor(p, 4); p += __shfl_xor(p, 8);
                    if ((lane & 15) == 0 && row < M) {
                        float* lo = (v == 0) ? lo0 : (v == 1) ? lo1 : lo2;
                        lo[row * 4 + wc] = p;
                    }
                }
            }
        }
    } else if (MODE == 1) {
        float p = 0.f;
        float qv[4];
#pragma unroll
        for (int n = 0; n < 4; ++n) qv[n] = vq[colbase + n * 16];
#pragma unroll
        for (int n = 0; n < 4; ++n) {
#pragma unroll
            for (int m = 0; m < 4; ++m) {
                long row = row0 + rbase + m * 16;
#pragma unroll
                for (int j = 0; j < 4; ++j)
                    if (row + j < M) p += qv[n] * tanhf(acc[m][n][j] + bv[n]);
            }
        }
#pragma unroll
        for (int off = 32; off > 0; off >>= 1) p += __shfl_xor(p, off);
        if (lane == 0) red8[wid] = p;
        __syncthreads();
        if (t == 0) {
            float s = 0.f;
#pragma unroll
            for (int i = 0; i < 8; ++i) s += red8[i];
            atomicAdd(&scoreSlot[blockIdx.y], s);
        }
    } else {
        float* redC = (float*)sm;   // reuse tile buffer (free after final barrier)
        float b2v = b2p[0];
        float wv[4];
#pragma unroll
        for (int n = 0; n < 4; ++n) wv[n] = vq[colbase + n * 16];
#pragma unroll
        for (int m = 0; m < 4; ++m) {
#pragma unroll
            for (int j = 0; j < 4; ++j) {
                float s = 0.f;
#pragma unroll
                for (int n = 0; n < 4; ++n)
                    s += fmaxf(acc[m][n][j] + bv[n], 0.f) * wv[n];
                s += __shfl_xor(s, 1); s += __shfl_xor(s, 2);
                s += __shfl_xor(s, 4); s += __shfl_xor(s, 8);
                if ((lane & 15) == 0) {
                    int lrow = wr * 64 + m * 16 + ((lane >> 4) << 2) + j;
                    redC[lrow * 4 + wc] = s;
                }
            }
        }
        __syncthreads();
        if (t < 128) {
            long row = row0 + t;
            if (row < M)
                outf[row] = redC[t * 4 + 0] + redC[t * 4 + 1]
                          + redC[t * 4 + 2] + redC[t * 4 + 3] + b2v;
        }
    }
}

// ---------------- merged weight transposes: Wt[n][k] = bf16(W[k][n]) ----------------
__global__ void transpose_cast4(const float* __restrict__ W0, const float* __restrict__ W1s,
                                const float* __restrict__ W2s, const float* __restrict__ W3s,
                                unsigned short* __restrict__ T0, unsigned short* __restrict__ T1,
                                unsigned short* __restrict__ T2, unsigned short* __restrict__ T3)
{
    const float* W = (blockIdx.y == 0) ? W0 : (blockIdx.y == 1) ? W1s : (blockIdx.y == 2) ? W2s : W3s;
    unsigned short* T = (blockIdx.y == 0) ? T0 : (blockIdx.y == 1) ? T1 : (blockIdx.y == 2) ? T2 : T3;
    int n = blockIdx.x, k = threadIdx.x;
    T[n * 256 + k] = f2bf(W[k * 256 + n]);
}

// ---------------- CSR build (both edge types via blockIdx.y) ----------------
__global__ void hist2(const int* __restrict__ d0, int E0, int* __restrict__ g0,
                      const int* __restrict__ d1, int E1, int* __restrict__ g1)
{
    int e = blockIdx.x * 256 + threadIdx.x;
    if (blockIdx.y == 0) { if (e < E0) atomicAdd(&g0[d0[e]], 1); }
    else                 { if (e < E1) atomicAdd(&g1[d1[e]], 1); }
}

__global__ void scan_bsum2(const int* __restrict__ g0, const int* __restrict__ g1, int n,
                           int* __restrict__ p0, int* __restrict__ p1)
{
    const int* deg = blockIdx.y ? g1 : g0;
    int* part      = blockIdx.y ? p1 : p0;
    __shared__ int smem[SCAN_B];
    int i = blockIdx.x * SCAN_B + threadIdx.x;
    smem[threadIdx.x] = (i < n) ? deg[i] : 0;
    __syncthreads();
    for (int off = SCAN_B / 2; off > 0; off >>= 1) {
        if (threadIdx.x < off) smem[threadIdx.x] += smem[threadIdx.x + off];
        __syncthreads();
    }
    if (threadIdx.x == 0) part[blockIdx.x] = smem[0];
}

__global__ void scan_part2(int* __restrict__ p0, int* __restrict__ p1, int nb)
{
    int* part = blockIdx.y ? p1 : p0;
    __shared__ int smem[1024];
    int t = threadIdx.x;
    int v = (t < nb) ? part[t] : 0;
    smem[t] = v;
    __syncthreads();
    for (int off = 1; off < 1024; off <<= 1) {
        int add = (t >= off) ? smem[t - off] : 0;
        __syncthreads();
        smem[t] += add;
        __syncthreads();
    }
    if (t < nb) part[t] = smem[t] - v;
}

__global__ void scan_final2(const int* __restrict__ g0, const int* __restrict__ g1, int n,
                            const int* __restrict__ p0, const int* __restrict__ p1,
                            int* __restrict__ r0, int* __restrict__ r1, int E0, int E1)
{
    const int* deg = blockIdx.y ? g1 : g0;
    const int* part = blockIdx.y ? p1 : p0;
    int* rowptr = blockIdx.y ? r1 : r0;
    int E = blockIdx.y ? E1 : E0;
    __shared__ int smem[SCAN_B];
    int t = threadIdx.x;
    int i = blockIdx.x * SCAN_B + t;
    int v = (i < n) ? deg[i] : 0;
    smem[t] = v;
    __syncthreads();
    for (int off = 1; off < SCAN_B; off <<= 1) {
        int add = (t >= off) ? smem[t - off] : 0;
        __syncthreads();
        smem[t] += add;
        __syncthreads();
    }
    if (i < n) rowptr[i] = part[blockIdx.x] + smem[t] - v;
    if (blockIdx.x == 0 && t == 0) rowptr[n] = E;
}

__global__ void fill_csr2(const int* __restrict__ d0, int E0, const int* __restrict__ r0,
                          int* __restrict__ c0, int* __restrict__ o0,
                          const int* __restrict__ d1, int E1, const int* __restrict__ r1,
                          int* __restrict__ c1, int* __restrict__ o1)
{
    int e = blockIdx.x * 256 + threadIdx.x;
    if (blockIdx.y == 0) {
        if (e < E0) { int d = d0[e]; int s = atomicAdd(&c0[d], 1); o0[r0[d] + s] = e; }
    } else {
        if (e < E1) { int d = d1[e]; int s = atomicAdd(&c1[d], 1); o1[r1[d] + s] = e; }
    }
}

// ======== fused per-dst GAT (merged over gridDim.y = 2 edge types) ========
// one wave per dst node; softmax in-wave; HALF-WAVE gather: lanes 0-31 = edge i,
// lanes 32-63 = edge i+1, each lane covers 8 dims (16B dwordx4 load). Batched x2.
__launch_bounds__(256)
__global__ void gat_fused(const unsigned short* __restrict__ xs0,
                          const unsigned short* __restrict__ xs1,
                          const float* __restrict__ als0, const float* __restrict__ als1,
                          const float* __restrict__ ald0, const float* __restrict__ ald1,
                          const int* __restrict__ rp0, const int* __restrict__ rp1,
                          const int* __restrict__ csr0, const int* __restrict__ csr1,
                          const int* __restrict__ src0, const int* __restrict__ src1,
                          int N,
                          unsigned short* __restrict__ out0,
                          unsigned short* __restrict__ out1)
{
    const int et = blockIdx.y;
    const unsigned short* xsrc = et ? xs1 : xs0;
    const float* als = et ? als1 : als0;
    const float* ald = et ? ald1 : ald0;
    const int* rowptr = et ? rp1 : rp0;
    const int* csr    = et ? csr1 : csr0;
    const int* src    = et ? src1 : src0;
    unsigned short* outb = et ? out1 : out0;

    __shared__ float lw[4][64 * 4];
    __shared__ int   ls[4][64];
    const int wv   = threadIdx.x >> 6;
    const int w    = (int)((blockIdx.x * 256 + threadIdx.x) >> 6);
    const int lane = threadIdx.x & 63;
    if (w >= N) return;
    const int beg = rowptr[w], end = rowptr[w + 1];
    const int deg = end - beg;
    const int sub = lane & 31, half = lane >> 5;
    const int h2 = sub >> 3;                     // head of this lane's 8 dims
    const float4 d4 = *(const float4*)&ald[(size_t)w * 4];
    const size_t loff8 = (size_t)(sub << 3);     // element offset of this lane's dims

    float a8A[8] = {0.f, 0.f, 0.f, 0.f, 0.f, 0.f, 0.f, 0.f};
    float a8B[8] = {0.f, 0.f, 0.f, 0.f, 0.f, 0.f, 0.f, 0.f};
    float dn0 = 0.f, dn1 = 0.f, dn2 = 0.f, dn3 = 0.f;

    if (deg <= 64) {
        // ---- phase 1: lane-per-edge softmax weights ----
        float al0 = NEG_BIG, al1 = NEG_BIG, al2 = NEG_BIG, al3 = NEG_BIG;
        int es = 0;
        if (lane < deg) {
            int e = csr[beg + lane];
            es = src[e];
            float4 a = *(const float4*)&als[(size_t)es * 4];
            al0 = lrelu(a.x + d4.x); al1 = lrelu(a.y + d4.y);
            al2 = lrelu(a.z + d4.z); al3 = lrelu(a.w + d4.w);
        }
        float m0 = al0, m1 = al1, m2 = al2, m3 = al3;
#pragma unroll
        for (int off = 32; off > 0; off >>= 1) {
            m0 = fmaxf(m0, __shfl_xor(m0, off));
            m1 = fmaxf(m1, __shfl_xor(m1, off));
            m2 = fmaxf(m2, __shfl_xor(m2, off));
            m3 = fmaxf(m3, __shfl_xor(m3, off));
        }
        float w0 = 0.f, w1 = 0.f, w2 = 0.f, w3 = 0.f;
        if (lane < deg) {
            w0 = expf(al0 - m0); w1 = expf(al1 - m1);
            w2 = expf(al2 - m2); w3 = expf(al3 - m3);
            ls[wv][lane] = es;
            lw[wv][lane * 4 + 0] = w0; lw[wv][lane * 4 + 1] = w1;
            lw[wv][lane * 4 + 2] = w2; lw[wv][lane * 4 + 3] = w3;
        }
        dn0 = w0; dn1 = w1; dn2 = w2; dn3 = w3;

        // ---- phase 2: half-wave gather, 4 edges in flight ----
        int i = 0;
        for (; i + 4 <= deg; i += 4) {
            int eA = i + half, eB = i + 2 + half;
            int sA = ls[wv][eA], sB = ls[wv][eB];
            float wA = lw[wv][eA * 4 + h2], wB = lw[wv][eB * 4 + h2];
            uint4 xA = *(const uint4*)&xsrc[(size_t)sA * 256 + loff8];
            uint4 xB = *(const uint4*)&xsrc[(size_t)sB * 256 + loff8];
            fma8(a8A, xA, wA);
            fma8(a8B, xB, wB);
        }
        if (i + 2 <= deg) {
            int eA = i + half;
            int sA = ls[wv][eA];
            float wA = lw[wv][eA * 4 + h2];
            uint4 xA = *(const uint4*)&xsrc[(size_t)sA * 256 + loff8];
            fma8(a8A, xA, wA);
            i += 2;
        }
        if (i < deg) {   // odd leftover: half 1 contributes 0
            int sA = ls[wv][i];
            float wA = half ? 0.f : lw[wv][i * 4 + h2];
            uint4 xA = *(const uint4*)&xsrc[(size_t)sA * 256 + loff8];
            fma8(a8A, xA, wA);
        }
    } else {
        // ---- general path (rare): pass 1 = global max, pass 2 = exp + gather ----
        float m0 = NEG_BIG, m1 = NEG_BIG, m2 = NEG_BIG, m3 = NEG_BIG;
        for (int c = beg; c < end; c += 64) {
            if (c + lane < end) {
                int e = csr[c + lane];
                int s = src[e];
                float4 a = *(const float4*)&als[(size_t)s * 4];
                m0 = fmaxf(m0, lrelu(a.x + d4.x)); m1 = fmaxf(m1, lrelu(a.y + d4.y));
                m2 = fmaxf(m2, lrelu(a.z + d4.z)); m3 = fmaxf(m3, lrelu(a.w + d4.w));
            }
        }
#pragma unroll
        for (int off = 32; off > 0; off >>= 1) {
            m0 = fmaxf(m0, __shfl_xor(m0, off));
            m1 = fmaxf(m1, __shfl_xor(m1, off));
            m2 = fmaxf(m2, __shfl_xor(m2, off));
            m3 = fmaxf(m3, __shfl_xor(m3, off));
        }
        for (int c = beg; c < end; c += 64) {
            int cnt = min(64, end - c);
            if (lane < cnt) {
                int e = csr[c + lane];
                int es = src[e];
                float4 a = *(const float4*)&als[(size_t)es * 4];
                float w0 = expf(lrelu(a.x + d4.x) - m0);
                float w1 = expf(lrelu(a.y + d4.y) - m1);
                float w2 = expf(lrelu(a.z + d4.z) - m2);
                float w3 = expf(lrelu(a.w + d4.w) - m3);
                ls[wv][lane] = es;
                lw[wv][lane * 4 + 0] = w0; lw[wv][lane * 4 + 1] = w1;
                lw[wv][lane * 4 + 2] = w2; lw[wv][lane * 4 + 3] = w3;
                dn0 += w0; dn1 += w1; dn2 += w2; dn3 += w3;
            }
            int i = 0;
            for (; i + 4 <= cnt; i += 4) {
                int eA = i + half, eB = i + 2 + half;
                int sA = ls[wv][eA], sB = ls[wv][eB];
                float wA = lw[wv][eA * 4 + h2], wB = lw[wv][eB * 4 + h2];
                uint4 xA = *(const uint4*)&xsrc[(size_t)sA * 256 + loff8];
                uint4 xB = *(const uint4*)&xsrc[(size_t)sB * 256 + loff8];
                fma8(a8A, xA, wA);
                fma8(a8B, xB, wB);
            }
            if (i + 2 <= cnt) {
                int eA = i + half;
                int sA = ls[wv][eA];
                float wA = lw[wv][eA * 4 + h2];
                uint4 xA = *(const uint4*)&xsrc[(size_t)sA * 256 + loff8];
                fma8(a8A, xA, wA);
                i += 2;
            }
            if (i < cnt) {
                int sA = ls[wv][i];
                float wA = half ? 0.f : lw[wv][i * 4 + h2];
                uint4 xA = *(const uint4*)&xsrc[(size_t)sA * 256 + loff8];
                fma8(a8A, xA, wA);
            }
        }
    }

    // combine the two half-wave accumulators, then across the half boundary
#pragma unroll
    for (int j = 0; j < 8; ++j) a8A[j] += a8B[j];
#pragma unroll
    for (int j = 0; j < 8; ++j) a8A[j] += __shfl_xor(a8A[j], 32);

    // reduce denominators across lanes, select this lane's head
#pragma unroll
    for (int off = 32; off > 0; off >>= 1) {
        dn0 += __shfl_xor(dn0, off);
        dn1 += __shfl_xor(dn1, off);
        dn2 += __shfl_xor(dn2, off);
        dn3 += __shfl_xor(dn3, off);
    }
    float dh = (h2 == 0) ? dn0 : (h2 == 1) ? dn1 : (h2 == 2) ? dn2 : dn3;
    float inv = 1.f / (dh + 1e-16f);
    if (half == 0) {
        uint4 o;
        o.x = (unsigned)f2bf(fmaxf(a8A[0] * inv, 0.f)) | ((unsigned)f2bf(fmaxf(a8A[1] * inv, 0.f)) << 16);
        o.y = (unsigned)f2bf(fmaxf(a8A[2] * inv, 0.f)) | ((unsigned)f2bf(fmaxf(a8A[3] * inv, 0.f)) << 16);
        o.z = (unsigned)f2bf(fmaxf(a8A[4] * inv, 0.f)) | ((unsigned)f2bf(fmaxf(a8A[5] * inv, 0.f)) << 16);
        o.w = (unsigned)f2bf(fmaxf(a8A[6] * inv, 0.f)) | ((unsigned)f2bf(fmaxf(a8A[7] * inv, 0.f)) << 16);
        *(uint4*)&outb[(size_t)w * 256 + loff8] = o;
    }
}

__global__ void attn_k(const float* __restrict__ score, float* __restrict__ attn, float invN)
{
    if (threadIdx.x == 0 && blockIdx.x == 0) {
        float s0 = score[0] * invN, s1 = score[1] * invN;
        float m  = fmaxf(s0, s1);
        float e0 = expf(s0 - m), e1 = expf(s1 - m);
        float dsum = e0 + e1;
        attn[0] = e0 / dsum;
        attn[1] = e1 / dsum;
    }
}

extern "C" void kernel_launch(void* const* d_in, const int* in_sizes, int n_in,
                              void* d_out, int out_size, void* d_ws, size_t ws_size,
                              hipStream_t stream)
{
    const float* x_job    = (const float*)d_in[0];
    const float* x_skill  = (const float*)d_in[1];
    const float* W_job    = (const float*)d_in[2];
    const float* b_job    = (const float*)d_in[3];
    const float* W_skill  = (const float*)d_in[4];
    const float* b_skill  = (const float*)d_in[5];
    const float* a_src_sj = (const float*)d_in[6];
    const float* a_dst_sj = (const float*)d_in[7];
    const float* a_src_jj = (const float*)d_in[8];
    const float* a_dst_jj = (const float*)d_in[9];
    // d_in[10], d_in[11]: a_src_js / a_dst_js — js edge-type output unused by the head; skipped.
    const float* q_vec = (const float*)d_in[12];
    const float* Wk    = (const float*)d_in[13];
    const float* bk    = (const float*)d_in[14];
    const float* W1    = (const float*)d_in[15];
    const float* b1    = (const float*)d_in[16];
    const float* W2    = (const float*)d_in[17];
    const float* b2    = (const float*)d_in[18];
    const int* ei_sj_src = (const int*)d_in[19];
    const int* ei_sj_dst = (const int*)d_in[20];
    const int* ei_jj_src = (const int*)d_in[21];
    const int* ei_jj_dst = (const int*)d_in[22];

    const int NJ   = in_sizes[0] / 256;
    const int NS   = in_sizes[1] / 256;
    const int E_sj = in_sizes[19];
    const int E_jj = in_sizes[21];
    const int Emax = (E_sj > E_jj) ? E_sj : E_jj;
    const int gmJ  = (NJ + 127) / 128, gmS = (NS + 127) / 128;
    const long MpadJ = (long)gmJ * 128, MpadS = (long)gmS * 128;

    char* ws   = (char*)d_ws;
    size_t off = 0;
    auto alloc = [&](size_t bytes) { void* p = ws + off; off += (bytes + 255) & ~(size_t)255; return p; };
    unsigned short* h_job_bf   = (unsigned short*)alloc(MpadJ * 256 * 2);   // bf16 h tables
    unsigned short* h_skill_bf = (unsigned short*)alloc(MpadS * 256 * 2);
    unsigned short* Wjob_t  = (unsigned short*)alloc(256 * 256 * 2);
    unsigned short* Wskl_t  = (unsigned short*)alloc(256 * 256 * 2);
    unsigned short* Wk_t    = (unsigned short*)alloc(256 * 256 * 2);
    unsigned short* W1_t    = (unsigned short*)alloc(256 * 256 * 2);
    unsigned short* out_sj_bf = (unsigned short*)alloc(MpadJ * 256 * 2);
    unsigned short* out_jj_bf = (unsigned short*)alloc(MpadJ * 256 * 2);
    float* ald_sj  = (float*)alloc((size_t)NJ * 4 * 4);
    float* als_jj  = (float*)alloc((size_t)NJ * 4 * 4);
    float* ald_jj  = (float*)alloc((size_t)NJ * 4 * 4);
    float* als_sj  = (float*)alloc((size_t)NS * 4 * 4);
    float* score  = (float*)alloc(64 * 4);   // [0..1] raw scores, [2..3] attn
    float* attn   = score + 2;
    int* deg_sj = (int*)alloc((size_t)NJ * 4);
    int* deg_jj = (int*)alloc((size_t)NJ * 4);
    int* rp_sj  = (int*)alloc(((size_t)NJ + 1) * 4);
    int* rp_jj  = (int*)alloc(((size_t)NJ + 1) * 4);
    int* part_a = (int*)alloc(1024 * 4);
    int* part_b = (int*)alloc(1024 * 4);
    int* cur_sj = (int*)alloc((size_t)NJ * 4);
    int* cur_jj = (int*)alloc((size_t)NJ * 4);
    int* csr_sj = (int*)alloc((size_t)E_sj * 4);
    int* csr_jj = (int*)alloc((size_t)E_jj * 4);
    (void)ws_size; (void)n_in;

    hipMemsetAsync(score,  0, 2 * 4, stream);
    hipMemsetAsync(deg_sj, 0, (size_t)NJ * 4, stream);
    hipMemsetAsync(deg_jj, 0, (size_t)NJ * 4, stream);
    hipMemsetAsync(cur_sj, 0, (size_t)NJ * 4, stream);
    hipMemsetAsync(cur_jj, 0, (size_t)NJ * 4, stream);

    dim3 blk(256);
    int nbJ = (NJ + SCAN_B - 1) / SCAN_B;

    // ---- weight transposes (one launch) ----
    transpose_cast4<<<dim3(256, 4), blk, 0, stream>>>(
        W_job, W_skill, Wk, W1, Wjob_t, Wskl_t, Wk_t, W1_t);

    // ---- CSR build (merged pairs) ----
    hist2<<<dim3((Emax + 255) / 256, 2), blk, 0, stream>>>(
        ei_sj_dst, E_sj, deg_sj, ei_jj_dst, E_jj, deg_jj);
    scan_bsum2<<<dim3(nbJ, 2), dim3(SCAN_B), 0, stream>>>(deg_sj, deg_jj, NJ, part_a, part_b);
    scan_part2<<<dim3(1, 2), dim3(1024), 0, stream>>>(part_a, part_b, nbJ);
    scan_final2<<<dim3(nbJ, 2), dim3(SCAN_B), 0, stream>>>(
        deg_sj, deg_jj, NJ, part_a, part_b, rp_sj, rp_jj, E_sj, E_jj);
    fill_csr2<<<dim3((Emax + 255) / 256, 2), blk, 0, stream>>>(
        ei_sj_dst, E_sj, rp_sj, cur_sj, csr_sj,
        ei_jj_dst, E_jj, rp_jj, cur_jj, csr_jj);

    // ---- input projections (MFMA, f32 A staged+cast in-kernel) + fused logits ----
    gemm_mfma<0, 3, 1><<<dim3(gmJ), dim3(512), 0, stream>>>(
        x_job, nullptr, nullptr, Wjob_t, b_job, nullptr, nullptr, nullptr,
        h_job_bf, nullptr, nullptr,
        a_dst_sj, a_src_jj, a_dst_jj, ald_sj, als_jj, ald_jj, NJ);
    gemm_mfma<0, 1, 1><<<dim3(gmS), dim3(512), 0, stream>>>(
        x_skill, nullptr, nullptr, Wskl_t, b_skill, nullptr, nullptr, nullptr,
        h_skill_bf, nullptr, nullptr,
        a_src_sj, nullptr, nullptr, als_sj, nullptr, nullptr, NS);

    // ---- fused per-dst GAT, both edge types in one launch ----
    gat_fused<<<dim3((NJ + 3) / 4, 2), blk, 0, stream>>>(
        h_skill_bf, h_job_bf, als_sj, als_jj, ald_sj, ald_jj,
        rp_sj, rp_jj, csr_sj, csr_jj, ei_sj_src, ei_jj_src, NJ,
        out_sj_bf, out_jj_bf);

    // ---- semantic attention scores (both types in one launch) ----
    gemm_mfma<1, 0, 0><<<dim3(gmJ, 2), dim3(512), 0, stream>>>(
        nullptr, out_sj_bf, out_jj_bf, Wk_t, bk, q_vec, nullptr, nullptr,
        nullptr, nullptr, score,
        nullptr, nullptr, nullptr, nullptr, nullptr, nullptr, NJ);
    attn_k<<<1, 64, 0, stream>>>(score, attn, 1.0f / (float)NJ);

    // ---- head: blend fused into A-staging; relu+W2-dot+b2 epilogue ----
    gemm_mfma<2, 0, 0><<<dim3(gmJ), dim3(512), 0, stream>>>(
        nullptr, out_sj_bf, out_jj_bf, W1_t, b1, W2, b2, attn,
        nullptr, (float*)d_out, nullptr,
        nullptr, nullptr, nullptr, nullptr, nullptr, nullptr, NJ);
}